// Round 1
// baseline (915.508 us; speedup 1.0000x reference)
//
#include <hip/hip_runtime.h>

#define NEG_SLOPE 0.01f

// ============================ CSR build ============================

__global__ __launch_bounds__(256) void k_count(const int* __restrict__ dst,
                                               int* __restrict__ cnt, int E) {
  int e = blockIdx.x * 256 + threadIdx.x;
  if (e < E) atomicAdd(&cnt[dst[e]], 1);
}

__global__ __launch_bounds__(256) void k_dinv(const int* __restrict__ cnt,
                                              float* __restrict__ dinv, int n) {
  int i = blockIdx.x * 256 + threadIdx.x;
  if (i < n) dinv[i] = rsqrtf((float)cnt[i] + 1.0f);
}

// scan over cnt -> exclusive rowptr.  1024 elements per block (256 thr x 4).
__global__ __launch_bounds__(256) void k_scan1(const int* __restrict__ cnt,
                                               int* __restrict__ local,
                                               int* __restrict__ bsum, int n) {
  __shared__ int lds[256];
  int b = blockIdx.x, t = threadIdx.x;
  int base = b * 1024 + t * 4;
  int v0 = (base + 0 < n) ? cnt[base + 0] : 0;
  int v1 = (base + 1 < n) ? cnt[base + 1] : 0;
  int v2 = (base + 2 < n) ? cnt[base + 2] : 0;
  int v3 = (base + 3 < n) ? cnt[base + 3] : 0;
  int s = v0 + v1 + v2 + v3;
  lds[t] = s;
  __syncthreads();
  for (int ofs = 1; ofs < 256; ofs <<= 1) {
    int x = (t >= ofs) ? lds[t - ofs] : 0;
    __syncthreads();
    lds[t] += x;
    __syncthreads();
  }
  int run = lds[t] - s;  // exclusive prefix of this thread's chunk
  run += v0; if (base + 0 < n) local[base + 0] = run;
  run += v1; if (base + 1 < n) local[base + 1] = run;
  run += v2; if (base + 2 < n) local[base + 2] = run;
  run += v3; if (base + 3 < n) local[base + 3] = run;
  if (t == 255) bsum[b] = lds[255];
}

__global__ __launch_bounds__(64) void k_scan2(const int* __restrict__ bsum,
                                              int* __restrict__ bofs, int nb) {
  __shared__ int lds[64];
  int t = threadIdx.x;
  int v = (t < nb) ? bsum[t] : 0;
  lds[t] = v;
  __syncthreads();
  for (int ofs = 1; ofs < 64; ofs <<= 1) {
    int x = (t >= ofs) ? lds[t - ofs] : 0;
    __syncthreads();
    lds[t] += x;
    __syncthreads();
  }
  if (t < nb) bofs[t] = lds[t] - v;
}

__global__ __launch_bounds__(256) void k_scan3(const int* __restrict__ local,
                                               const int* __restrict__ bofs,
                                               int* __restrict__ rowptr, int n) {
  int i = blockIdx.x * 256 + threadIdx.x;
  if (i < n) rowptr[i + 1] = local[i] + bofs[i >> 10];
  if (i == 0) rowptr[0] = 0;
}

__global__ __launch_bounds__(256) void k_fill(const int* __restrict__ src,
                                              const int* __restrict__ dst,
                                              const int* __restrict__ rowptr,
                                              int* __restrict__ cursor,
                                              int* __restrict__ slot_src,
                                              float* __restrict__ slot_w,
                                              const float* __restrict__ dinv, int E) {
  int e = blockIdx.x * 256 + threadIdx.x;
  if (e < E) {
    int s = src[e], d = dst[e];
    int p = rowptr[d] + atomicAdd(&cursor[d], 1);
    slot_src[p] = s;
    slot_w[p] = dinv[s] * dinv[d];
  }
}

// ============================ SGEMM ============================
// C[N,M] = A[N,K] @ B[K,M] (+bias[M]) (+add[N,M]); K,M in {64,128}, K%16==0.
#define BM 128
#define BN 128
#define BK 16
#define TM 8
#define TN 8

__global__ __launch_bounds__(256) void k_sgemm(const float* __restrict__ A,
                                               const float* __restrict__ B,
                                               float* __restrict__ C, int N, int K,
                                               int M, const float* __restrict__ bias,
                                               const float* __restrict__ addp) {
  __shared__ float As[BK][BM + 4];  // +4 pad: row = 528B (16B aligned), kills store conflicts
  __shared__ float Bs[BK][BN + 4];
  int t = threadIdx.x;
  int row0 = blockIdx.x * BM;
  int col0 = blockIdx.y * BN;
  int tr = t >> 4, tc = t & 15;
  float acc[TM][TN] = {};
  for (int k0 = 0; k0 < K; k0 += BK) {
    // A tile: 128 rows x 16 k, float4 loads (2 per thread)
    for (int i = t; i < (BM * BK) / 4; i += 256) {
      int r = i >> 2;
      int kq = i & 3;
      int grow = row0 + r;
      float4 v = make_float4(0.f, 0.f, 0.f, 0.f);
      if (grow < N) v = *(const float4*)&A[(size_t)grow * K + k0 + kq * 4];
      As[kq * 4 + 0][r] = v.x;
      As[kq * 4 + 1][r] = v.y;
      As[kq * 4 + 2][r] = v.z;
      As[kq * 4 + 3][r] = v.w;
    }
    // B tile: 16 k x 128 cols
    for (int i = t; i < (BK * BN) / 4; i += 256) {
      int kk = i >> 5;
      int cq = i & 31;
      int gcol = col0 + cq * 4;
      float4 v = make_float4(0.f, 0.f, 0.f, 0.f);
      if (gcol < M) v = *(const float4*)&B[(size_t)(k0 + kk) * M + gcol];
      *(float4*)&Bs[kk][cq * 4] = v;
    }
    __syncthreads();
#pragma unroll
    for (int kk = 0; kk < BK; ++kk) {
      float ra[TM], rb[TN];
      *(float4*)&ra[0] = *(const float4*)&As[kk][tr * TM];
      *(float4*)&ra[4] = *(const float4*)&As[kk][tr * TM + 4];
      *(float4*)&rb[0] = *(const float4*)&Bs[kk][tc * TN];
      *(float4*)&rb[4] = *(const float4*)&Bs[kk][tc * TN + 4];
#pragma unroll
      for (int i = 0; i < TM; ++i)
#pragma unroll
        for (int j = 0; j < TN; ++j) acc[i][j] += ra[i] * rb[j];
    }
    __syncthreads();
  }
#pragma unroll
  for (int i = 0; i < TM; ++i) {
    int r = row0 + tr * TM + i;
    if (r >= N) continue;
#pragma unroll
    for (int j = 0; j < TN; ++j) {
      int c = col0 + tc * TN + j;
      if (c >= M) continue;
      float v = acc[i][j];
      if (bias) v += bias[c];
      if (addp) v += addp[(size_t)r * M + c];
      C[(size_t)r * M + c] = v;
    }
  }
}

// ============================ Aggregation ============================
// out[d] = sum_{e: dst=d} w_e * h[src_e] + dinv[d]^2 * h[d] + bias; optional leaky, resid.
// One wave per node; lane covers cols {2*lane, 2*lane+1} (float2).
__global__ __launch_bounds__(256) void k_agg128(const float* __restrict__ h,
                                                const int* __restrict__ rowptr,
                                                const int* __restrict__ slot_src,
                                                const float* __restrict__ slot_w,
                                                const float* __restrict__ dinv,
                                                const float* __restrict__ bias,
                                                const float* __restrict__ resid,
                                                float* __restrict__ out, int n,
                                                int leaky) {
  int w = (blockIdx.x * 256 + threadIdx.x) >> 6;
  int lane = threadIdx.x & 63;
  if (w >= n) return;
  int beg = rowptr[w], end = rowptr[w + 1];
  float a0 = 0.f, a1 = 0.f;
  for (int j = beg; j < end; ++j) {
    int s = slot_src[j];
    float wt = slot_w[j];
    float2 hv = *(const float2*)&h[(size_t)s * 128 + lane * 2];
    a0 += wt * hv.x;
    a1 += wt * hv.y;
  }
  float di = dinv[w];
  float sw = di * di;
  float2 hs = *(const float2*)&h[(size_t)w * 128 + lane * 2];
  a0 += sw * hs.x;
  a1 += sw * hs.y;
  a0 += bias[lane * 2];
  a1 += bias[lane * 2 + 1];
  if (leaky) {
    a0 = (a0 >= 0.f) ? a0 : NEG_SLOPE * a0;
    a1 = (a1 >= 0.f) ? a1 : NEG_SLOPE * a1;
  }
  if (resid) {
    float2 rv = *(const float2*)&resid[(size_t)w * 128 + lane * 2];
    a0 += rv.x;
    a1 += rv.y;
  }
  *(float2*)&out[(size_t)w * 128 + lane * 2] = make_float2(a0, a1);
}

// 64-dim variant (lane covers col = lane).
__global__ __launch_bounds__(256) void k_agg64(const float* __restrict__ h,
                                               const int* __restrict__ rowptr,
                                               const int* __restrict__ slot_src,
                                               const float* __restrict__ slot_w,
                                               const float* __restrict__ dinv,
                                               const float* __restrict__ bias,
                                               float* __restrict__ out, int n,
                                               int leaky) {
  int w = (blockIdx.x * 256 + threadIdx.x) >> 6;
  int lane = threadIdx.x & 63;
  if (w >= n) return;
  int beg = rowptr[w], end = rowptr[w + 1];
  float a0 = 0.f;
  for (int j = beg; j < end; ++j) {
    int s = slot_src[j];
    float wt = slot_w[j];
    a0 += wt * h[(size_t)s * 64 + lane];
  }
  float di = dinv[w];
  a0 += di * di * h[(size_t)w * 64 + lane];
  a0 += bias[lane];
  if (leaky) a0 = (a0 >= 0.f) ? a0 : NEG_SLOPE * a0;
  out[(size_t)w * 64 + lane] = a0;
}

// ============================ launcher ============================

extern "C" void kernel_launch(void* const* d_in, const int* in_sizes, int n_in,
                              void* d_out, int out_size, void* d_ws, size_t ws_size,
                              hipStream_t stream) {
  const float* x   = (const float*)d_in[0];
  const int* eidx  = (const int*)d_in[1];
  const float* W1  = (const float*)d_in[2];
  const float* b1  = (const float*)d_in[3];
  const float* W2  = (const float*)d_in[4];
  const float* b2  = (const float*)d_in[5];
  const float* W3  = (const float*)d_in[6];
  const float* b3  = (const float*)d_in[7];
  const float* W4  = (const float*)d_in[8];
  const float* b4  = (const float*)d_in[9];
  const float* W5  = (const float*)d_in[10];
  const float* b5  = (const float*)d_in[11];
  const float* Wd  = (const float*)d_in[12];
  const float* bd  = (const float*)d_in[13];

  const int N = in_sizes[0] / 128;  // 50000
  const int E = in_sizes[1] / 2;    // 800000
  const int* srcA = eidx;           // edge_index[0]
  const int* dstA = eidx + E;       // edge_index[1]

  // workspace carve-up (256B aligned slots)
  char* ws = (char*)d_ws;
  size_t off = 0;
  auto carve = [&](size_t bytes) {
    char* p = ws + off;
    off = (off + bytes + 255) & ~(size_t)255;
    return p;
  };
  int*   cnt      = (int*)carve((size_t)N * 4);
  int*   rowptr   = (int*)carve((size_t)(N + 1) * 4);
  int*   cursor   = (int*)carve((size_t)N * 4);
  int*   local    = (int*)carve((size_t)N * 4);
  int*   bsum     = (int*)carve(64 * 4);
  int*   bofs     = (int*)carve(64 * 4);
  float* dinv     = (float*)carve((size_t)N * 4);
  int*   slot_src = (int*)carve((size_t)E * 4);
  float* slot_w   = (float*)carve((size_t)E * 4);
  float* bufA     = (float*)carve((size_t)N * 128 * 4);
  float* bufB     = (float*)carve((size_t)N * 128 * 4);
  float* bufC     = (float*)carve((size_t)N * 128 * 4);

  float* recon = (float*)d_out;                 // [N,128]
  float* zout  = (float*)d_out + (size_t)N * 128;  // [N,64]

  const int nb = (N + 1023) / 1024;  // 49 scan blocks (<=64)
  dim3 b256(256);

  // ---- CSR build (edge structure is layer-invariant) ----
  hipMemsetAsync(cnt, 0, (size_t)N * 4, stream);
  hipMemsetAsync(cursor, 0, (size_t)N * 4, stream);
  k_count<<<(E + 255) / 256, b256, 0, stream>>>(dstA, cnt, E);
  k_dinv<<<(N + 255) / 256, b256, 0, stream>>>(cnt, dinv, N);
  k_scan1<<<nb, b256, 0, stream>>>(cnt, local, bsum, N);
  k_scan2<<<1, 64, 0, stream>>>(bsum, bofs, nb);
  k_scan3<<<(N + 255) / 256, b256, 0, stream>>>(local, bofs, rowptr, N);
  k_fill<<<(E + 255) / 256, b256, 0, stream>>>(srcA, dstA, rowptr, cursor, slot_src,
                                               slot_w, dinv, E);

  const int gemmBlocks = (N + BM - 1) / BM;  // 391
  const int aggBlocks  = (N * 64 + 255) / 256;  // wave per node

  // ---- layer 1: x1 = leaky(gcn(x, W1, b1)) -> bufB ----
  k_sgemm<<<dim3(gemmBlocks, 1), b256, 0, stream>>>(x, W1, bufA, N, 128, 128, nullptr, nullptr);
  k_agg128<<<aggBlocks, b256, 0, stream>>>(bufA, rowptr, slot_src, slot_w, dinv, b1,
                                           nullptr, bufB, N, 1);
  // ---- layer 2: x2 = leaky(gcn(x1, W2, b2)) -> bufC ----
  k_sgemm<<<dim3(gemmBlocks, 1), b256, 0, stream>>>(bufB, W2, bufA, N, 128, 128, nullptr, nullptr);
  k_agg128<<<aggBlocks, b256, 0, stream>>>(bufA, rowptr, slot_src, slot_w, dinv, b2,
                                           nullptr, bufC, N, 1);
  // ---- layer 3: x3 = leaky(gcn(x2, W3, b3)) + x2 -> bufB ----
  k_sgemm<<<dim3(gemmBlocks, 1), b256, 0, stream>>>(bufC, W3, bufA, N, 128, 128, nullptr, nullptr);
  k_agg128<<<aggBlocks, b256, 0, stream>>>(bufA, rowptr, slot_src, slot_w, dinv, b3,
                                           bufC, bufB, N, 1);
  // ---- layer 4: z = gcn(x3, W4, b4) -> zout (no activation) ----
  k_sgemm<<<dim3(gemmBlocks, 1), b256, 0, stream>>>(bufB, W4, bufA, N, 128, 64, nullptr, nullptr);
  k_agg64<<<aggBlocks, b256, 0, stream>>>(bufA, rowptr, slot_src, slot_w, dinv, b4,
                                          zout, N, 0);
  // ---- layer 5: xr = leaky(gcn(z, W5, b5)) -> bufC ----
  k_sgemm<<<dim3(gemmBlocks, 1), b256, 0, stream>>>(zout, W5, bufA, N, 64, 128, nullptr, nullptr);
  k_agg128<<<aggBlocks, b256, 0, stream>>>(bufA, rowptr, slot_src, slot_w, dinv, b5,
                                           nullptr, bufC, N, 1);
  // ---- decode: recon = xr @ Wd + bd + x ----
  k_sgemm<<<dim3(gemmBlocks, 1), b256, 0, stream>>>(bufC, Wd, recon, N, 128, 128, bd, x);
}

// Round 3
// 741.107 us; speedup vs baseline: 1.2353x; 1.2353x over previous
//
#include <hip/hip_runtime.h>

#define NEG_SLOPE 0.01f

// ============================ CSR build ============================

__global__ __launch_bounds__(256) void k_count(const int* __restrict__ dst,
                                               int* __restrict__ cnt, int E) {
  int e = blockIdx.x * 256 + threadIdx.x;
  if (e < E) atomicAdd(&cnt[dst[e]], 1);
}

__global__ __launch_bounds__(256) void k_dinv(const int* __restrict__ cnt,
                                              float* __restrict__ dinv, int n) {
  int i = blockIdx.x * 256 + threadIdx.x;
  if (i < n) dinv[i] = rsqrtf((float)cnt[i] + 1.0f);
}

// scan over cnt -> exclusive rowptr.  1024 elements per block (256 thr x 4).
__global__ __launch_bounds__(256) void k_scan1(const int* __restrict__ cnt,
                                               int* __restrict__ local,
                                               int* __restrict__ bsum, int n) {
  __shared__ int lds[256];
  int b = blockIdx.x, t = threadIdx.x;
  int base = b * 1024 + t * 4;
  int v0 = (base + 0 < n) ? cnt[base + 0] : 0;
  int v1 = (base + 1 < n) ? cnt[base + 1] : 0;
  int v2 = (base + 2 < n) ? cnt[base + 2] : 0;
  int v3 = (base + 3 < n) ? cnt[base + 3] : 0;
  int s = v0 + v1 + v2 + v3;
  lds[t] = s;
  __syncthreads();
  for (int ofs = 1; ofs < 256; ofs <<= 1) {
    int x = (t >= ofs) ? lds[t - ofs] : 0;
    __syncthreads();
    lds[t] += x;
    __syncthreads();
  }
  int run = lds[t] - s;  // exclusive prefix of this thread's chunk
  run += v0; if (base + 0 < n) local[base + 0] = run;
  run += v1; if (base + 1 < n) local[base + 1] = run;
  run += v2; if (base + 2 < n) local[base + 2] = run;
  run += v3; if (base + 3 < n) local[base + 3] = run;
  if (t == 255) bsum[b] = lds[255];
}

__global__ __launch_bounds__(64) void k_scan2(const int* __restrict__ bsum,
                                              int* __restrict__ bofs, int nb) {
  __shared__ int lds[64];
  int t = threadIdx.x;
  int v = (t < nb) ? bsum[t] : 0;
  lds[t] = v;
  __syncthreads();
  for (int ofs = 1; ofs < 64; ofs <<= 1) {
    int x = (t >= ofs) ? lds[t - ofs] : 0;
    __syncthreads();
    lds[t] += x;
    __syncthreads();
  }
  if (t < nb) bofs[t] = lds[t] - v;
}

__global__ __launch_bounds__(256) void k_scan3(const int* __restrict__ local,
                                               const int* __restrict__ bofs,
                                               int* __restrict__ rowptr, int n) {
  int i = blockIdx.x * 256 + threadIdx.x;
  if (i < n) rowptr[i + 1] = local[i] + bofs[i >> 10];
  if (i == 0) rowptr[0] = 0;
}

__global__ __launch_bounds__(256) void k_fill(const int* __restrict__ src,
                                              const int* __restrict__ dst,
                                              const int* __restrict__ rowptr,
                                              int* __restrict__ cursor,
                                              int* __restrict__ slot_src,
                                              float* __restrict__ slot_w,
                                              const float* __restrict__ dinv, int E) {
  int e = blockIdx.x * 256 + threadIdx.x;
  if (e < E) {
    int s = src[e], d = dst[e];
    int p = rowptr[d] + atomicAdd(&cursor[d], 1);
    slot_src[p] = s;
    slot_w[p] = dinv[s] * dinv[d];
  }
}

// ============================ SGEMM ============================
// C[N,M] = A[N,K] @ B[K,M] (+bias[M]) (leaky?) (+add[N,M]); K,M in {64,128}.
#define BM 128
#define BN 128
#define BK 32
#define TM 8
#define TN 8

__global__ __launch_bounds__(256) void k_sgemm(const float* __restrict__ A,
                                               const float* __restrict__ B,
                                               float* __restrict__ C, int N, int K,
                                               int M, const float* __restrict__ bias,
                                               int leaky,
                                               const float* __restrict__ addp) {
  __shared__ float As[BK][BM + 4];
  __shared__ float Bs[BK][BN + 4];
  int t = threadIdx.x;
  int row0 = blockIdx.x * BM;
  int col0 = blockIdx.y * BN;
  int tr = t >> 4, tc = t & 15;
  float acc[TM][TN] = {};
  for (int k0 = 0; k0 < K; k0 += BK) {
    // A tile: 128 rows x 32 k, float4 loads (4 per thread)
#pragma unroll
    for (int i = t; i < (BM * BK) / 4; i += 256) {
      int r = i >> 3;        // 8 float4 per row of 32 k
      int kq = i & 7;
      int grow = row0 + r;
      float4 v = make_float4(0.f, 0.f, 0.f, 0.f);
      if (grow < N) v = *(const float4*)&A[(size_t)grow * K + k0 + kq * 4];
      As[kq * 4 + 0][r] = v.x;
      As[kq * 4 + 1][r] = v.y;
      As[kq * 4 + 2][r] = v.z;
      As[kq * 4 + 3][r] = v.w;
    }
    // B tile: 32 k x 128 cols
#pragma unroll
    for (int i = t; i < (BK * BN) / 4; i += 256) {
      int kk = i >> 5;
      int cq = i & 31;
      int gcol = col0 + cq * 4;
      float4 v = make_float4(0.f, 0.f, 0.f, 0.f);
      if (gcol < M) v = *(const float4*)&B[(size_t)(k0 + kk) * M + gcol];
      *(float4*)&Bs[kk][cq * 4] = v;
    }
    __syncthreads();
#pragma unroll
    for (int kk = 0; kk < BK; ++kk) {
      float ra[TM], rb[TN];
      *(float4*)&ra[0] = *(const float4*)&As[kk][tr * TM];
      *(float4*)&ra[4] = *(const float4*)&As[kk][tr * TM + 4];
      *(float4*)&rb[0] = *(const float4*)&Bs[kk][tc * TN];
      *(float4*)&rb[4] = *(const float4*)&Bs[kk][tc * TN + 4];
#pragma unroll
      for (int i = 0; i < TM; ++i)
#pragma unroll
        for (int j = 0; j < TN; ++j) acc[i][j] += ra[i] * rb[j];
    }
    __syncthreads();
  }
#pragma unroll
  for (int i = 0; i < TM; ++i) {
    int r = row0 + tr * TM + i;
    if (r >= N) continue;
#pragma unroll
    for (int j = 0; j < TN; ++j) {
      int c = col0 + tc * TN + j;
      if (c >= M) continue;
      float v = acc[i][j];
      if (bias) v += bias[c];
      if (leaky) v = (v >= 0.f) ? v : NEG_SLOPE * v;
      if (addp) v += addp[(size_t)r * M + c];
      C[(size_t)r * M + c] = v;
    }
  }
}

// ============================ Aggregation ============================
// out[d] = sum_{e: dst=d} w_e * h[src_e] + dinv[d]^2 * h[d] (+bias) (leaky?) (+resid)
// One wave per node; lane covers cols {2*lane, 2*lane+1} (float2).
// 4-way edge unroll: 4 independent gathers in flight per wave (MLP).
__global__ __launch_bounds__(256) void k_agg128(const float* __restrict__ h,
                                                const int* __restrict__ rowptr,
                                                const int* __restrict__ slot_src,
                                                const float* __restrict__ slot_w,
                                                const float* __restrict__ dinv,
                                                const float* __restrict__ bias,
                                                const float* __restrict__ resid,
                                                float* __restrict__ out, int n,
                                                int leaky) {
  int w = (blockIdx.x * 256 + threadIdx.x) >> 6;
  int lane = threadIdx.x & 63;
  if (w >= n) return;
  int beg = rowptr[w], end = rowptr[w + 1];
  float a0 = 0.f, a1 = 0.f, c0 = 0.f, c1 = 0.f;
  int j = beg;
  for (; j + 4 <= end; j += 4) {
    int s0 = slot_src[j + 0], s1 = slot_src[j + 1];
    int s2 = slot_src[j + 2], s3 = slot_src[j + 3];
    float w0 = slot_w[j + 0], w1 = slot_w[j + 1];
    float w2 = slot_w[j + 2], w3 = slot_w[j + 3];
    float2 h0 = *(const float2*)&h[(size_t)s0 * 128 + lane * 2];
    float2 h1 = *(const float2*)&h[(size_t)s1 * 128 + lane * 2];
    float2 h2 = *(const float2*)&h[(size_t)s2 * 128 + lane * 2];
    float2 h3 = *(const float2*)&h[(size_t)s3 * 128 + lane * 2];
    a0 += w0 * h0.x; a1 += w0 * h0.y;
    c0 += w1 * h1.x; c1 += w1 * h1.y;
    a0 += w2 * h2.x; a1 += w2 * h2.y;
    c0 += w3 * h3.x; c1 += w3 * h3.y;
  }
  for (; j < end; ++j) {
    int s = slot_src[j];
    float wt = slot_w[j];
    float2 hv = *(const float2*)&h[(size_t)s * 128 + lane * 2];
    a0 += wt * hv.x;
    a1 += wt * hv.y;
  }
  a0 += c0; a1 += c1;
  float di = dinv[w];
  float sw = di * di;
  float2 hs = *(const float2*)&h[(size_t)w * 128 + lane * 2];
  a0 += sw * hs.x;
  a1 += sw * hs.y;
  if (bias) {
    a0 += bias[lane * 2];
    a1 += bias[lane * 2 + 1];
  }
  if (leaky) {
    a0 = (a0 >= 0.f) ? a0 : NEG_SLOPE * a0;
    a1 = (a1 >= 0.f) ? a1 : NEG_SLOPE * a1;
  }
  if (resid) {
    float2 rv = *(const float2*)&resid[(size_t)w * 128 + lane * 2];
    a0 += rv.x;
    a1 += rv.y;
  }
  *(float2*)&out[(size_t)w * 128 + lane * 2] = make_float2(a0, a1);
}

// 64-dim variant (lane covers col = lane), 4-way unroll.
__global__ __launch_bounds__(256) void k_agg64(const float* __restrict__ h,
                                               const int* __restrict__ rowptr,
                                               const int* __restrict__ slot_src,
                                               const float* __restrict__ slot_w,
                                               const float* __restrict__ dinv,
                                               const float* __restrict__ bias,
                                               float* __restrict__ out, int n,
                                               int leaky) {
  int w = (blockIdx.x * 256 + threadIdx.x) >> 6;
  int lane = threadIdx.x & 63;
  if (w >= n) return;
  int beg = rowptr[w], end = rowptr[w + 1];
  float a0 = 0.f, c0 = 0.f;
  int j = beg;
  for (; j + 4 <= end; j += 4) {
    int s0 = slot_src[j + 0], s1 = slot_src[j + 1];
    int s2 = slot_src[j + 2], s3 = slot_src[j + 3];
    float w0 = slot_w[j + 0], w1 = slot_w[j + 1];
    float w2 = slot_w[j + 2], w3 = slot_w[j + 3];
    float h0 = h[(size_t)s0 * 64 + lane];
    float h1 = h[(size_t)s1 * 64 + lane];
    float h2 = h[(size_t)s2 * 64 + lane];
    float h3 = h[(size_t)s3 * 64 + lane];
    a0 += w0 * h0;
    c0 += w1 * h1;
    a0 += w2 * h2;
    c0 += w3 * h3;
  }
  for (; j < end; ++j) {
    a0 += slot_w[j] * h[(size_t)slot_src[j] * 64 + lane];
  }
  a0 += c0;
  float di = dinv[w];
  a0 += di * di * h[(size_t)w * 64 + lane];
  if (bias) a0 += bias[lane];
  if (leaky) a0 = (a0 >= 0.f) ? a0 : NEG_SLOPE * a0;
  out[(size_t)w * 64 + lane] = a0;
}

// ============================ launcher ============================

extern "C" void kernel_launch(void* const* d_in, const int* in_sizes, int n_in,
                              void* d_out, int out_size, void* d_ws, size_t ws_size,
                              hipStream_t stream) {
  const float* x   = (const float*)d_in[0];
  const int* eidx  = (const int*)d_in[1];
  const float* W1  = (const float*)d_in[2];
  const float* b1  = (const float*)d_in[3];
  const float* W2  = (const float*)d_in[4];
  const float* b2  = (const float*)d_in[5];
  const float* W3  = (const float*)d_in[6];
  const float* b3  = (const float*)d_in[7];
  const float* W4  = (const float*)d_in[8];
  const float* b4  = (const float*)d_in[9];
  const float* W5  = (const float*)d_in[10];
  const float* b5  = (const float*)d_in[11];
  const float* Wd  = (const float*)d_in[12];
  const float* bd  = (const float*)d_in[13];

  const int N = in_sizes[0] / 128;  // 50000
  const int E = in_sizes[1] / 2;    // 800000
  const int* srcA = eidx;           // edge_index[0]
  const int* dstA = eidx + E;       // edge_index[1]

  // workspace carve-up (256B aligned slots)
  char* ws = (char*)d_ws;
  size_t off = 0;
  auto carve = [&](size_t bytes) {
    char* p = ws + off;
    off = (off + bytes + 255) & ~(size_t)255;
    return p;
  };
  int*   cnt      = (int*)carve((size_t)N * 4);
  int*   rowptr   = (int*)carve((size_t)(N + 1) * 4);
  int*   cursor   = (int*)carve((size_t)N * 4);
  int*   local    = (int*)carve((size_t)N * 4);
  int*   bsum     = (int*)carve(64 * 4);
  int*   bofs     = (int*)carve(64 * 4);
  float* dinv     = (float*)carve((size_t)N * 4);
  int*   slot_src = (int*)carve((size_t)E * 4);
  float* slot_w   = (float*)carve((size_t)E * 4);
  float* bufA     = (float*)carve((size_t)N * 128 * 4);
  float* bufB     = (float*)carve((size_t)N * 128 * 4);
  float* bufC     = (float*)carve((size_t)N * 128 * 4);

  float* recon = (float*)d_out;                    // [N,128]
  float* zout  = (float*)d_out + (size_t)N * 128;  // [N,64]

  const int nb = (N + 1023) / 1024;  // scan blocks (<=64)
  dim3 b256(256);

  // ---- CSR build (edge structure is layer-invariant) ----
  hipMemsetAsync(cnt, 0, (size_t)N * 4, stream);
  hipMemsetAsync(cursor, 0, (size_t)N * 4, stream);
  k_count<<<(E + 255) / 256, b256, 0, stream>>>(dstA, cnt, E);
  k_dinv<<<(N + 255) / 256, b256, 0, stream>>>(cnt, dinv, N);
  k_scan1<<<nb, b256, 0, stream>>>(cnt, local, bsum, N);
  k_scan2<<<1, 64, 0, stream>>>(bsum, bofs, nb);
  k_scan3<<<(N + 255) / 256, b256, 0, stream>>>(local, bofs, rowptr, N);
  k_fill<<<(E + 255) / 256, b256, 0, stream>>>(srcA, dstA, rowptr, cursor, slot_src,
                                               slot_w, dinv, E);

  const int gemmBlocks = (N + BM - 1) / BM;       // 391
  const int aggBlocks  = (N * 64 + 255) / 256;    // wave per node

  // ---- layer 1: x1 = leaky(gcn(x, W1, b1)) -> bufB ----
  k_sgemm<<<dim3(gemmBlocks, 1), b256, 0, stream>>>(x, W1, bufA, N, 128, 128, nullptr, 0, nullptr);
  k_agg128<<<aggBlocks, b256, 0, stream>>>(bufA, rowptr, slot_src, slot_w, dinv, b1,
                                           nullptr, bufB, N, 1);
  // ---- layer 2: x2 = leaky(gcn(x1, W2, b2)) -> bufC ----
  k_sgemm<<<dim3(gemmBlocks, 1), b256, 0, stream>>>(bufB, W2, bufA, N, 128, 128, nullptr, 0, nullptr);
  k_agg128<<<aggBlocks, b256, 0, stream>>>(bufA, rowptr, slot_src, slot_w, dinv, b2,
                                           nullptr, bufC, N, 1);
  // ---- layer 3: x3 = leaky(gcn(x2, W3, b3)) + x2 -> bufB ----
  k_sgemm<<<dim3(gemmBlocks, 1), b256, 0, stream>>>(bufC, W3, bufA, N, 128, 128, nullptr, 0, nullptr);
  k_agg128<<<aggBlocks, b256, 0, stream>>>(bufA, rowptr, slot_src, slot_w, dinv, b3,
                                           bufC, bufB, N, 1);
  // ---- layer 4: z = gcn(x3, W4, b4) -> zout (no activation) ----
  k_sgemm<<<dim3(gemmBlocks, 1), b256, 0, stream>>>(bufB, W4, bufA, N, 128, 64, nullptr, 0, nullptr);
  k_agg64<<<aggBlocks, b256, 0, stream>>>(bufA, rowptr, slot_src, slot_w, dinv, b4,
                                          zout, N, 0);
  // ---- layer 5 (agg-first, linearity): za = agg64(z); xr = leaky(za@W5 + b5) ----
  k_agg64<<<aggBlocks, b256, 0, stream>>>(zout, rowptr, slot_src, slot_w, dinv, nullptr,
                                          bufA, N, 0);
  k_sgemm<<<dim3(gemmBlocks, 1), b256, 0, stream>>>(bufA, W5, bufC, N, 64, 128, b5, 1, nullptr);
  // ---- decode: recon = xr @ Wd + bd + x ----
  k_sgemm<<<dim3(gemmBlocks, 1), b256, 0, stream>>>(bufC, Wd, recon, N, 128, 128, bd, 0, x);
}

// Round 10
// 600.988 us; speedup vs baseline: 1.5233x; 1.2331x over previous
//
#include <hip/hip_runtime.h>

#define NEG_SLOPE 0.01f

// ============================ CSR build ============================

__global__ __launch_bounds__(256) void k_count(const int* __restrict__ dst,
                                               int* __restrict__ cnt, int E) {
  int e = blockIdx.x * 256 + threadIdx.x;
  if (e < E) atomicAdd(&cnt[dst[e]], 1);
}

__global__ __launch_bounds__(256) void k_dinv(const int* __restrict__ cnt,
                                              float* __restrict__ dinv, int n) {
  int i = blockIdx.x * 256 + threadIdx.x;
  if (i < n) dinv[i] = rsqrtf((float)cnt[i] + 1.0f);
}

// scan over cnt -> exclusive rowptr.  1024 elements per block (256 thr x 4).
__global__ __launch_bounds__(256) void k_scan1(const int* __restrict__ cnt,
                                               int* __restrict__ local,
                                               int* __restrict__ bsum, int n) {
  __shared__ int lds[256];
  int b = blockIdx.x, t = threadIdx.x;
  int base = b * 1024 + t * 4;
  int v0 = (base + 0 < n) ? cnt[base + 0] : 0;
  int v1 = (base + 1 < n) ? cnt[base + 1] : 0;
  int v2 = (base + 2 < n) ? cnt[base + 2] : 0;
  int v3 = (base + 3 < n) ? cnt[base + 3] : 0;
  int s = v0 + v1 + v2 + v3;
  lds[t] = s;
  __syncthreads();
  for (int ofs = 1; ofs < 256; ofs <<= 1) {
    int x = (t >= ofs) ? lds[t - ofs] : 0;
    __syncthreads();
    lds[t] += x;
    __syncthreads();
  }
  int run = lds[t] - s;  // exclusive prefix of this thread's chunk
  run += v0; if (base + 0 < n) local[base + 0] = run;
  run += v1; if (base + 1 < n) local[base + 1] = run;
  run += v2; if (base + 2 < n) local[base + 2] = run;
  run += v3; if (base + 3 < n) local[base + 3] = run;
  if (t == 255) bsum[b] = lds[255];
}

__global__ __launch_bounds__(64) void k_scan2(const int* __restrict__ bsum,
                                              int* __restrict__ bofs, int nb) {
  __shared__ int lds[64];
  int t = threadIdx.x;
  int v = (t < nb) ? bsum[t] : 0;
  lds[t] = v;
  __syncthreads();
  for (int ofs = 1; ofs < 64; ofs <<= 1) {
    int x = (t >= ofs) ? lds[t - ofs] : 0;
    __syncthreads();
    lds[t] += x;
    __syncthreads();
  }
  if (t < nb) bofs[t] = lds[t] - v;
}

__global__ __launch_bounds__(256) void k_scan3(const int* __restrict__ local,
                                               const int* __restrict__ bofs,
                                               int* __restrict__ rowptr, int n) {
  int i = blockIdx.x * 256 + threadIdx.x;
  if (i < n) rowptr[i + 1] = local[i] + bofs[i >> 10];
  if (i == 0) rowptr[0] = 0;
}

__global__ __launch_bounds__(256) void k_fill(const int* __restrict__ src,
                                              const int* __restrict__ dst,
                                              const int* __restrict__ rowptr,
                                              int* __restrict__ cursor,
                                              int* __restrict__ slot_src,
                                              float* __restrict__ slot_w,
                                              const float* __restrict__ dinv, int E) {
  int e = blockIdx.x * 256 + threadIdx.x;
  if (e < E) {
    int s = src[e], d = dst[e];
    int p = rowptr[d] + atomicAdd(&cursor[d], 1);
    slot_src[p] = s;
    slot_w[p] = dinv[s] * dinv[d];
  }
}

// ============================ SGEMM ============================
// C[N,M] = A[N,K] @ B[K,M] (+bias[M]) (leaky?) (+add[N,M]); K,M in {64,128}.
// 64x64 tile, 256 threads, 4x4 microtile.  Grid: (M/BN, ceil(N/BM)) so the
// col-blocks sharing an A-tile are linearly adjacent (same-XCD L2 reuse).
#define BM 64
#define BN 64
#define BK 32
#define TM 4
#define TN 4

__global__ __launch_bounds__(256) void k_sgemm(const float* __restrict__ A,
                                               const float* __restrict__ B,
                                               float* __restrict__ C, int N, int K,
                                               int M, const float* __restrict__ bias,
                                               int leaky,
                                               const float* __restrict__ addp) {
  __shared__ float As[BK][BM + 4];  // 68 floats/row = 272B (16B-aligned)
  __shared__ float Bs[BK][BN + 4];
  int t = threadIdx.x;
  int col0 = blockIdx.x * BN;
  int row0 = blockIdx.y * BM;
  int tr = t >> 4, tc = t & 15;  // 16x16 threads, each 4x4 outputs
  float acc[TM][TN] = {};
  for (int k0 = 0; k0 < K; k0 += BK) {
    // A tile: 64 rows x 32 k = 512 float4, transposed store into As[k][row]
#pragma unroll
    for (int i = t; i < (BM * BK) / 4; i += 256) {
      int r = i >> 3;   // 8 float4 per row
      int kq = i & 7;
      int grow = row0 + r;
      float4 v = make_float4(0.f, 0.f, 0.f, 0.f);
      if (grow < N) v = *(const float4*)&A[(size_t)grow * K + k0 + kq * 4];
      As[kq * 4 + 0][r] = v.x;
      As[kq * 4 + 1][r] = v.y;
      As[kq * 4 + 2][r] = v.z;
      As[kq * 4 + 3][r] = v.w;
    }
    // B tile: 32 k x 64 cols = 512 float4
#pragma unroll
    for (int i = t; i < (BK * BN) / 4; i += 256) {
      int kk = i >> 4;  // 16 float4 per row
      int cq = i & 15;
      float4 v = *(const float4*)&B[(size_t)(k0 + kk) * M + col0 + cq * 4];
      *(float4*)&Bs[kk][cq * 4] = v;
    }
    __syncthreads();
#pragma unroll
    for (int kk = 0; kk < BK; ++kk) {
      float ra[TM], rb[TN];
      *(float4*)&ra[0] = *(const float4*)&As[kk][tr * TM];
      *(float4*)&rb[0] = *(const float4*)&Bs[kk][tc * TN];
#pragma unroll
      for (int i = 0; i < TM; ++i)
#pragma unroll
        for (int j = 0; j < TN; ++j) acc[i][j] += ra[i] * rb[j];
    }
    __syncthreads();
  }
#pragma unroll
  for (int i = 0; i < TM; ++i) {
    int r = row0 + tr * TM + i;
    if (r >= N) continue;
#pragma unroll
    for (int j = 0; j < TN; ++j) {
      int c = col0 + tc * TN + j;
      float v = acc[i][j];
      if (bias) v += bias[c];
      if (leaky) v = (v >= 0.f) ? v : NEG_SLOPE * v;
      if (addp) v += addp[(size_t)r * M + c];
      C[(size_t)r * M + c] = v;
    }
  }
}

// ============================ Aggregation ============================
// out[d] = sum_{e: dst=d} w_e * h[src_e] + dinv[d]^2 * h[d] (+bias) (leaky?) (+resid)
// One wave per node; lane covers cols {2*lane, 2*lane+1} (float2).
// 8-way edge unroll: 8 independent gathers in flight per wave (MLP).
__global__ __launch_bounds__(256) void k_agg128(const float* __restrict__ h,
                                                const int* __restrict__ rowptr,
                                                const int* __restrict__ slot_src,
                                                const float* __restrict__ slot_w,
                                                const float* __restrict__ dinv,
                                                const float* __restrict__ bias,
                                                const float* __restrict__ resid,
                                                float* __restrict__ out, int n,
                                                int leaky) {
  int w = (blockIdx.x * 256 + threadIdx.x) >> 6;
  int lane = threadIdx.x & 63;
  if (w >= n) return;
  int beg = rowptr[w], end = rowptr[w + 1];
  float a0 = 0.f, a1 = 0.f, c0 = 0.f, c1 = 0.f;
  int j = beg;
  for (; j + 8 <= end; j += 8) {
    int s0 = slot_src[j + 0], s1 = slot_src[j + 1];
    int s2 = slot_src[j + 2], s3 = slot_src[j + 3];
    int s4 = slot_src[j + 4], s5 = slot_src[j + 5];
    int s6 = slot_src[j + 6], s7 = slot_src[j + 7];
    float w0 = slot_w[j + 0], w1 = slot_w[j + 1];
    float w2 = slot_w[j + 2], w3 = slot_w[j + 3];
    float w4 = slot_w[j + 4], w5 = slot_w[j + 5];
    float w6 = slot_w[j + 6], w7 = slot_w[j + 7];
    float2 h0 = *(const float2*)&h[(size_t)s0 * 128 + lane * 2];
    float2 h1 = *(const float2*)&h[(size_t)s1 * 128 + lane * 2];
    float2 h2 = *(const float2*)&h[(size_t)s2 * 128 + lane * 2];
    float2 h3 = *(const float2*)&h[(size_t)s3 * 128 + lane * 2];
    float2 h4 = *(const float2*)&h[(size_t)s4 * 128 + lane * 2];
    float2 h5 = *(const float2*)&h[(size_t)s5 * 128 + lane * 2];
    float2 h6 = *(const float2*)&h[(size_t)s6 * 128 + lane * 2];
    float2 h7 = *(const float2*)&h[(size_t)s7 * 128 + lane * 2];
    a0 += w0 * h0.x; a1 += w0 * h0.y;
    c0 += w1 * h1.x; c1 += w1 * h1.y;
    a0 += w2 * h2.x; a1 += w2 * h2.y;
    c0 += w3 * h3.x; c1 += w3 * h3.y;
    a0 += w4 * h4.x; a1 += w4 * h4.y;
    c0 += w5 * h5.x; c1 += w5 * h5.y;
    a0 += w6 * h6.x; a1 += w6 * h6.y;
    c0 += w7 * h7.x; c1 += w7 * h7.y;
  }
  for (; j + 4 <= end; j += 4) {
    int s0 = slot_src[j + 0], s1 = slot_src[j + 1];
    int s2 = slot_src[j + 2], s3 = slot_src[j + 3];
    float w0 = slot_w[j + 0], w1 = slot_w[j + 1];
    float w2 = slot_w[j + 2], w3 = slot_w[j + 3];
    float2 h0 = *(const float2*)&h[(size_t)s0 * 128 + lane * 2];
    float2 h1 = *(const float2*)&h[(size_t)s1 * 128 + lane * 2];
    float2 h2 = *(const float2*)&h[(size_t)s2 * 128 + lane * 2];
    float2 h3 = *(const float2*)&h[(size_t)s3 * 128 + lane * 2];
    a0 += w0 * h0.x; a1 += w0 * h0.y;
    c0 += w1 * h1.x; c1 += w1 * h1.y;
    a0 += w2 * h2.x; a1 += w2 * h2.y;
    c0 += w3 * h3.x; c1 += w3 * h3.y;
  }
  for (; j < end; ++j) {
    int s = slot_src[j];
    float wt = slot_w[j];
    float2 hv = *(const float2*)&h[(size_t)s * 128 + lane * 2];
    a0 += wt * hv.x;
    a1 += wt * hv.y;
  }
  a0 += c0; a1 += c1;
  float di = dinv[w];
  float sw = di * di;
  float2 hs = *(const float2*)&h[(size_t)w * 128 + lane * 2];
  a0 += sw * hs.x;
  a1 += sw * hs.y;
  if (bias) {
    a0 += bias[lane * 2];
    a1 += bias[lane * 2 + 1];
  }
  if (leaky) {
    a0 = (a0 >= 0.f) ? a0 : NEG_SLOPE * a0;
    a1 = (a1 >= 0.f) ? a1 : NEG_SLOPE * a1;
  }
  if (resid) {
    float2 rv = *(const float2*)&resid[(size_t)w * 128 + lane * 2];
    a0 += rv.x;
    a1 += rv.y;
  }
  *(float2*)&out[(size_t)w * 128 + lane * 2] = make_float2(a0, a1);
}

// 64-dim variant (lane covers col = lane), 8-way unroll.
__global__ __launch_bounds__(256) void k_agg64(const float* __restrict__ h,
                                               const int* __restrict__ rowptr,
                                               const int* __restrict__ slot_src,
                                               const float* __restrict__ slot_w,
                                               const float* __restrict__ dinv,
                                               const float* __restrict__ bias,
                                               float* __restrict__ out, int n,
                                               int leaky) {
  int w = (blockIdx.x * 256 + threadIdx.x) >> 6;
  int lane = threadIdx.x & 63;
  if (w >= n) return;
  int beg = rowptr[w], end = rowptr[w + 1];
  float a0 = 0.f, c0 = 0.f;
  int j = beg;
  for (; j + 8 <= end; j += 8) {
    int s0 = slot_src[j + 0], s1 = slot_src[j + 1];
    int s2 = slot_src[j + 2], s3 = slot_src[j + 3];
    int s4 = slot_src[j + 4], s5 = slot_src[j + 5];
    int s6 = slot_src[j + 6], s7 = slot_src[j + 7];
    float w0 = slot_w[j + 0], w1 = slot_w[j + 1];
    float w2 = slot_w[j + 2], w3 = slot_w[j + 3];
    float w4 = slot_w[j + 4], w5 = slot_w[j + 5];
    float w6 = slot_w[j + 6], w7 = slot_w[j + 7];
    float h0 = h[(size_t)s0 * 64 + lane];
    float h1 = h[(size_t)s1 * 64 + lane];
    float h2 = h[(size_t)s2 * 64 + lane];
    float h3 = h[(size_t)s3 * 64 + lane];
    float h4 = h[(size_t)s4 * 64 + lane];
    float h5 = h[(size_t)s5 * 64 + lane];
    float h6 = h[(size_t)s6 * 64 + lane];
    float h7 = h[(size_t)s7 * 64 + lane];
    a0 += w0 * h0;
    c0 += w1 * h1;
    a0 += w2 * h2;
    c0 += w3 * h3;
    a0 += w4 * h4;
    c0 += w5 * h5;
    a0 += w6 * h6;
    c0 += w7 * h7;
  }
  for (; j + 4 <= end; j += 4) {
    int s0 = slot_src[j + 0], s1 = slot_src[j + 1];
    int s2 = slot_src[j + 2], s3 = slot_src[j + 3];
    float w0 = slot_w[j + 0], w1 = slot_w[j + 1];
    float w2 = slot_w[j + 2], w3 = slot_w[j + 3];
    float h0 = h[(size_t)s0 * 64 + lane];
    float h1 = h[(size_t)s1 * 64 + lane];
    float h2 = h[(size_t)s2 * 64 + lane];
    float h3 = h[(size_t)s3 * 64 + lane];
    a0 += w0 * h0;
    c0 += w1 * h1;
    a0 += w2 * h2;
    c0 += w3 * h3;
  }
  for (; j < end; ++j) {
    a0 += slot_w[j] * h[(size_t)slot_src[j] * 64 + lane];
  }
  a0 += c0;
  float di = dinv[w];
  a0 += di * di * h[(size_t)w * 64 + lane];
  if (bias) a0 += bias[lane];
  if (leaky) a0 = (a0 >= 0.f) ? a0 : NEG_SLOPE * a0;
  out[(size_t)w * 64 + lane] = a0;
}

// ============================ launcher ============================

extern "C" void kernel_launch(void* const* d_in, const int* in_sizes, int n_in,
                              void* d_out, int out_size, void* d_ws, size_t ws_size,
                              hipStream_t stream) {
  const float* x   = (const float*)d_in[0];
  const int* eidx  = (const int*)d_in[1];
  const float* W1  = (const float*)d_in[2];
  const float* b1  = (const float*)d_in[3];
  const float* W2  = (const float*)d_in[4];
  const float* b2  = (const float*)d_in[5];
  const float* W3  = (const float*)d_in[6];
  const float* b3  = (const float*)d_in[7];
  const float* W4  = (const float*)d_in[8];
  const float* b4  = (const float*)d_in[9];
  const float* W5  = (const float*)d_in[10];
  const float* b5  = (const float*)d_in[11];
  const float* Wd  = (const float*)d_in[12];
  const float* bd  = (const float*)d_in[13];

  const int N = in_sizes[0] / 128;  // 50000
  const int E = in_sizes[1] / 2;    // 800000
  const int* srcA = eidx;           // edge_index[0]
  const int* dstA = eidx + E;       // edge_index[1]

  // workspace carve-up (256B aligned slots)
  char* ws = (char*)d_ws;
  size_t off = 0;
  auto carve = [&](size_t bytes) {
    char* p = ws + off;
    off = (off + bytes + 255) & ~(size_t)255;
    return p;
  };
  int*   cnt      = (int*)carve((size_t)N * 4);
  int*   rowptr   = (int*)carve((size_t)(N + 1) * 4);
  int*   cursor   = (int*)carve((size_t)N * 4);
  int*   local    = (int*)carve((size_t)N * 4);
  int*   bsum     = (int*)carve(64 * 4);
  int*   bofs     = (int*)carve(64 * 4);
  float* dinv     = (float*)carve((size_t)N * 4);
  int*   slot_src = (int*)carve((size_t)E * 4);
  float* slot_w   = (float*)carve((size_t)E * 4);
  float* bufA     = (float*)carve((size_t)N * 128 * 4);
  float* bufB     = (float*)carve((size_t)N * 128 * 4);
  float* bufC     = (float*)carve((size_t)N * 128 * 4);

  float* recon = (float*)d_out;                    // [N,128]
  float* zout  = (float*)d_out + (size_t)N * 128;  // [N,64]

  const int nb = (N + 1023) / 1024;  // scan blocks (<=64)
  dim3 b256(256);

  // ---- CSR build (edge structure is layer-invariant) ----
  hipMemsetAsync(cnt, 0, (size_t)N * 4, stream);
  hipMemsetAsync(cursor, 0, (size_t)N * 4, stream);
  k_count<<<(E + 255) / 256, b256, 0, stream>>>(dstA, cnt, E);
  k_dinv<<<(N + 255) / 256, b256, 0, stream>>>(cnt, dinv, N);
  k_scan1<<<nb, b256, 0, stream>>>(cnt, local, bsum, N);
  k_scan2<<<1, 64, 0, stream>>>(bsum, bofs, nb);
  k_scan3<<<(N + 255) / 256, b256, 0, stream>>>(local, bofs, rowptr, N);
  k_fill<<<(E + 255) / 256, b256, 0, stream>>>(srcA, dstA, rowptr, cursor, slot_src,
                                               slot_w, dinv, E);

  const int rowBlocks = (N + BM - 1) / BM;        // 782
  const int aggBlocks = (N * 64 + 255) / 256;     // wave per node
  dim3 g128(128 / BN, rowBlocks);                 // (2, 782)
  dim3 g64(64 / BN, rowBlocks);                   // (1, 782)

  // ---- layer 1: x1 = leaky(gcn(x, W1, b1)) -> bufB ----
  k_sgemm<<<g128, b256, 0, stream>>>(x, W1, bufA, N, 128, 128, nullptr, 0, nullptr);
  k_agg128<<<aggBlocks, b256, 0, stream>>>(bufA, rowptr, slot_src, slot_w, dinv, b1,
                                           nullptr, bufB, N, 1);
  // ---- layer 2: x2 = leaky(gcn(x1, W2, b2)) -> bufC ----
  k_sgemm<<<g128, b256, 0, stream>>>(bufB, W2, bufA, N, 128, 128, nullptr, 0, nullptr);
  k_agg128<<<aggBlocks, b256, 0, stream>>>(bufA, rowptr, slot_src, slot_w, dinv, b2,
                                           nullptr, bufC, N, 1);
  // ---- layer 3: x3 = leaky(gcn(x2, W3, b3)) + x2 -> bufB ----
  k_sgemm<<<g128, b256, 0, stream>>>(bufC, W3, bufA, N, 128, 128, nullptr, 0, nullptr);
  k_agg128<<<aggBlocks, b256, 0, stream>>>(bufA, rowptr, slot_src, slot_w, dinv, b3,
                                           bufC, bufB, N, 1);
  // ---- layer 4: z = gcn(x3, W4, b4) -> zout (no activation) ----
  k_sgemm<<<g64, b256, 0, stream>>>(bufB, W4, bufA, N, 128, 64, nullptr, 0, nullptr);
  k_agg64<<<aggBlocks, b256, 0, stream>>>(bufA, rowptr, slot_src, slot_w, dinv, b4,
                                          zout, N, 0);
  // ---- layer 5 (agg-first, linearity): za = agg64(z); xr = leaky(za@W5 + b5) ----
  k_agg64<<<aggBlocks, b256, 0, stream>>>(zout, rowptr, slot_src, slot_w, dinv, nullptr,
                                          bufA, N, 0);
  k_sgemm<<<g128, b256, 0, stream>>>(bufA, W5, bufC, N, 64, 128, b5, 1, nullptr);
  // ---- decode: recon = xr @ Wd + bd + x ----
  k_sgemm<<<g128, b256, 0, stream>>>(bufC, Wd, recon, N, 128, 128, bd, 0, x);
}

// Round 12
// 517.810 us; speedup vs baseline: 1.7680x; 1.1606x over previous
//
#include <hip/hip_runtime.h>
#include <hip/hip_fp16.h>

#define NEG_SLOPE 0.01f

// ============================ CSR build ============================

__global__ __launch_bounds__(256) void k_count(const int* __restrict__ dst,
                                               int* __restrict__ cnt, int E) {
  int e = blockIdx.x * 256 + threadIdx.x;
  if (e < E) atomicAdd(&cnt[dst[e]], 1);
}

__global__ __launch_bounds__(256) void k_dinv(const int* __restrict__ cnt,
                                              float* __restrict__ dinv, int n) {
  int i = blockIdx.x * 256 + threadIdx.x;
  if (i < n) dinv[i] = rsqrtf((float)cnt[i] + 1.0f);
}

// scan over cnt -> exclusive rowptr.  1024 elements per block (256 thr x 4).
__global__ __launch_bounds__(256) void k_scan1(const int* __restrict__ cnt,
                                               int* __restrict__ local,
                                               int* __restrict__ bsum, int n) {
  __shared__ int lds[256];
  int b = blockIdx.x, t = threadIdx.x;
  int base = b * 1024 + t * 4;
  int v0 = (base + 0 < n) ? cnt[base + 0] : 0;
  int v1 = (base + 1 < n) ? cnt[base + 1] : 0;
  int v2 = (base + 2 < n) ? cnt[base + 2] : 0;
  int v3 = (base + 3 < n) ? cnt[base + 3] : 0;
  int s = v0 + v1 + v2 + v3;
  lds[t] = s;
  __syncthreads();
  for (int ofs = 1; ofs < 256; ofs <<= 1) {
    int x = (t >= ofs) ? lds[t - ofs] : 0;
    __syncthreads();
    lds[t] += x;
    __syncthreads();
  }
  int run = lds[t] - s;  // exclusive prefix of this thread's chunk
  run += v0; if (base + 0 < n) local[base + 0] = run;
  run += v1; if (base + 1 < n) local[base + 1] = run;
  run += v2; if (base + 2 < n) local[base + 2] = run;
  run += v3; if (base + 3 < n) local[base + 3] = run;
  if (t == 255) bsum[b] = lds[255];
}

__global__ __launch_bounds__(64) void k_scan2(const int* __restrict__ bsum,
                                              int* __restrict__ bofs, int nb) {
  __shared__ int lds[64];
  int t = threadIdx.x;
  int v = (t < nb) ? bsum[t] : 0;
  lds[t] = v;
  __syncthreads();
  for (int ofs = 1; ofs < 64; ofs <<= 1) {
    int x = (t >= ofs) ? lds[t - ofs] : 0;
    __syncthreads();
    lds[t] += x;
    __syncthreads();
  }
  if (t < nb) bofs[t] = lds[t] - v;
}

__global__ __launch_bounds__(256) void k_scan3(const int* __restrict__ local,
                                               const int* __restrict__ bofs,
                                               int* __restrict__ rowptr, int n) {
  int i = blockIdx.x * 256 + threadIdx.x;
  if (i < n) rowptr[i + 1] = local[i] + bofs[i >> 10];
  if (i == 0) rowptr[0] = 0;
}

__global__ __launch_bounds__(256) void k_fill(const int* __restrict__ src,
                                              const int* __restrict__ dst,
                                              const int* __restrict__ rowptr,
                                              int* __restrict__ cursor,
                                              int* __restrict__ slot_src,
                                              float* __restrict__ slot_w,
                                              const float* __restrict__ dinv, int E) {
  int e = blockIdx.x * 256 + threadIdx.x;
  if (e < E) {
    int s = src[e], d = dst[e];
    int p = rowptr[d] + atomicAdd(&cursor[d], 1);
    slot_src[p] = s;
    slot_w[p] = dinv[s] * dinv[d];
  }
}

// ============================ SGEMM ============================
// C[N,M] = A[N,K] @ B[K,M] (+bias[M]) (leaky?) (+add[N,M]); K,M in {64,128}.
// If C16 != null, writes fp16 (pre-agg intermediate path; no epilogue ops).
#define BM 64
#define BN 64
#define BK 32
#define TM 4
#define TN 4

__global__ __launch_bounds__(256) void k_sgemm(const float* __restrict__ A,
                                               const float* __restrict__ B,
                                               float* __restrict__ C,
                                               __half* __restrict__ C16, int N, int K,
                                               int M, const float* __restrict__ bias,
                                               int leaky,
                                               const float* __restrict__ addp) {
  __shared__ float As[BK][BM + 4];  // 68 floats/row = 272B (16B-aligned)
  __shared__ float Bs[BK][BN + 4];
  int t = threadIdx.x;
  int col0 = blockIdx.x * BN;
  int row0 = blockIdx.y * BM;
  int tr = t >> 4, tc = t & 15;  // 16x16 threads, each 4x4 outputs
  float acc[TM][TN] = {};
  for (int k0 = 0; k0 < K; k0 += BK) {
    // A tile: 64 rows x 32 k = 512 float4, transposed store into As[k][row]
#pragma unroll
    for (int i = t; i < (BM * BK) / 4; i += 256) {
      int r = i >> 3;   // 8 float4 per row
      int kq = i & 7;
      int grow = row0 + r;
      float4 v = make_float4(0.f, 0.f, 0.f, 0.f);
      if (grow < N) v = *(const float4*)&A[(size_t)grow * K + k0 + kq * 4];
      As[kq * 4 + 0][r] = v.x;
      As[kq * 4 + 1][r] = v.y;
      As[kq * 4 + 2][r] = v.z;
      As[kq * 4 + 3][r] = v.w;
    }
    // B tile: 32 k x 64 cols = 512 float4
#pragma unroll
    for (int i = t; i < (BK * BN) / 4; i += 256) {
      int kk = i >> 4;  // 16 float4 per row
      int cq = i & 15;
      float4 v = *(const float4*)&B[(size_t)(k0 + kk) * M + col0 + cq * 4];
      *(float4*)&Bs[kk][cq * 4] = v;
    }
    __syncthreads();
#pragma unroll
    for (int kk = 0; kk < BK; ++kk) {
      float ra[TM], rb[TN];
      *(float4*)&ra[0] = *(const float4*)&As[kk][tr * TM];
      *(float4*)&rb[0] = *(const float4*)&Bs[kk][tc * TN];
#pragma unroll
      for (int i = 0; i < TM; ++i)
#pragma unroll
        for (int j = 0; j < TN; ++j) acc[i][j] += ra[i] * rb[j];
    }
    __syncthreads();
  }
#pragma unroll
  for (int i = 0; i < TM; ++i) {
    int r = row0 + tr * TM + i;
    if (r >= N) continue;
    if (C16) {
      // fp16 intermediate path (no bias/leaky/addp on this path)
#pragma unroll
      for (int j = 0; j < TN; j += 2) {
        int c = col0 + tc * TN + j;
        *(__half2*)&C16[(size_t)r * M + c] =
            __floats2half2_rn(acc[i][j], acc[i][j + 1]);
      }
    } else {
#pragma unroll
      for (int j = 0; j < TN; ++j) {
        int c = col0 + tc * TN + j;
        float v = acc[i][j];
        if (bias) v += bias[c];
        if (leaky) v = (v >= 0.f) ? v : NEG_SLOPE * v;
        if (addp) v += addp[(size_t)r * M + c];
        C[(size_t)r * M + c] = v;
      }
    }
  }
}

// ============================ Aggregation ============================
// out[d] = sum_{e: dst=d} w_e * h[src_e] + dinv[d]^2 * h[d] (+bias) (leaky?) (+resid)
// h is fp16 (halved gather traffic); accumulate fp32.  One wave per node;
// lane covers cols {2*lane, 2*lane+1}.  8-way edge unroll (MLP).
__global__ __launch_bounds__(256) void k_agg128(const __half* __restrict__ h,
                                                const int* __restrict__ rowptr,
                                                const int* __restrict__ slot_src,
                                                const float* __restrict__ slot_w,
                                                const float* __restrict__ dinv,
                                                const float* __restrict__ bias,
                                                const float* __restrict__ resid,
                                                float* __restrict__ out, int n,
                                                int leaky) {
  int w = (blockIdx.x * 256 + threadIdx.x) >> 6;
  int lane = threadIdx.x & 63;
  if (w >= n) return;
  int beg = rowptr[w], end = rowptr[w + 1];
  float a0 = 0.f, a1 = 0.f, c0 = 0.f, c1 = 0.f;
  int j = beg;
  for (; j + 8 <= end; j += 8) {
    int s0 = slot_src[j + 0], s1 = slot_src[j + 1];
    int s2 = slot_src[j + 2], s3 = slot_src[j + 3];
    int s4 = slot_src[j + 4], s5 = slot_src[j + 5];
    int s6 = slot_src[j + 6], s7 = slot_src[j + 7];
    float w0 = slot_w[j + 0], w1 = slot_w[j + 1];
    float w2 = slot_w[j + 2], w3 = slot_w[j + 3];
    float w4 = slot_w[j + 4], w5 = slot_w[j + 5];
    float w6 = slot_w[j + 6], w7 = slot_w[j + 7];
    float2 h0 = __half22float2(*(const __half2*)&h[(size_t)s0 * 128 + lane * 2]);
    float2 h1 = __half22float2(*(const __half2*)&h[(size_t)s1 * 128 + lane * 2]);
    float2 h2 = __half22float2(*(const __half2*)&h[(size_t)s2 * 128 + lane * 2]);
    float2 h3 = __half22float2(*(const __half2*)&h[(size_t)s3 * 128 + lane * 2]);
    float2 h4 = __half22float2(*(const __half2*)&h[(size_t)s4 * 128 + lane * 2]);
    float2 h5 = __half22float2(*(const __half2*)&h[(size_t)s5 * 128 + lane * 2]);
    float2 h6 = __half22float2(*(const __half2*)&h[(size_t)s6 * 128 + lane * 2]);
    float2 h7 = __half22float2(*(const __half2*)&h[(size_t)s7 * 128 + lane * 2]);
    a0 += w0 * h0.x; a1 += w0 * h0.y;
    c0 += w1 * h1.x; c1 += w1 * h1.y;
    a0 += w2 * h2.x; a1 += w2 * h2.y;
    c0 += w3 * h3.x; c1 += w3 * h3.y;
    a0 += w4 * h4.x; a1 += w4 * h4.y;
    c0 += w5 * h5.x; c1 += w5 * h5.y;
    a0 += w6 * h6.x; a1 += w6 * h6.y;
    c0 += w7 * h7.x; c1 += w7 * h7.y;
  }
  for (; j + 4 <= end; j += 4) {
    int s0 = slot_src[j + 0], s1 = slot_src[j + 1];
    int s2 = slot_src[j + 2], s3 = slot_src[j + 3];
    float w0 = slot_w[j + 0], w1 = slot_w[j + 1];
    float w2 = slot_w[j + 2], w3 = slot_w[j + 3];
    float2 h0 = __half22float2(*(const __half2*)&h[(size_t)s0 * 128 + lane * 2]);
    float2 h1 = __half22float2(*(const __half2*)&h[(size_t)s1 * 128 + lane * 2]);
    float2 h2 = __half22float2(*(const __half2*)&h[(size_t)s2 * 128 + lane * 2]);
    float2 h3 = __half22float2(*(const __half2*)&h[(size_t)s3 * 128 + lane * 2]);
    a0 += w0 * h0.x; a1 += w0 * h0.y;
    c0 += w1 * h1.x; c1 += w1 * h1.y;
    a0 += w2 * h2.x; a1 += w2 * h2.y;
    c0 += w3 * h3.x; c1 += w3 * h3.y;
  }
  for (; j < end; ++j) {
    int s = slot_src[j];
    float wt = slot_w[j];
    float2 hv = __half22float2(*(const __half2*)&h[(size_t)s * 128 + lane * 2]);
    a0 += wt * hv.x;
    a1 += wt * hv.y;
  }
  a0 += c0; a1 += c1;
  float di = dinv[w];
  float sw = di * di;
  float2 hs = __half22float2(*(const __half2*)&h[(size_t)w * 128 + lane * 2]);
  a0 += sw * hs.x;
  a1 += sw * hs.y;
  if (bias) {
    a0 += bias[lane * 2];
    a1 += bias[lane * 2 + 1];
  }
  if (leaky) {
    a0 = (a0 >= 0.f) ? a0 : NEG_SLOPE * a0;
    a1 = (a1 >= 0.f) ? a1 : NEG_SLOPE * a1;
  }
  if (resid) {
    float2 rv = *(const float2*)&resid[(size_t)w * 128 + lane * 2];
    a0 += rv.x;
    a1 += rv.y;
  }
  *(float2*)&out[(size_t)w * 128 + lane * 2] = make_float2(a0, a1);
}

// 64-dim variant (lane covers col = lane), fp16 gather, 8-way unroll.
// Optionally also writes an fp16 twin of the output (for a later gather pass).
__global__ __launch_bounds__(256) void k_agg64(const __half* __restrict__ h,
                                               const int* __restrict__ rowptr,
                                               const int* __restrict__ slot_src,
                                               const float* __restrict__ slot_w,
                                               const float* __restrict__ dinv,
                                               const float* __restrict__ bias,
                                               float* __restrict__ out,
                                               __half* __restrict__ out16, int n,
                                               int leaky) {
  int w = (blockIdx.x * 256 + threadIdx.x) >> 6;
  int lane = threadIdx.x & 63;
  if (w >= n) return;
  int beg = rowptr[w], end = rowptr[w + 1];
  float a0 = 0.f, c0 = 0.f;
  int j = beg;
  for (; j + 8 <= end; j += 8) {
    int s0 = slot_src[j + 0], s1 = slot_src[j + 1];
    int s2 = slot_src[j + 2], s3 = slot_src[j + 3];
    int s4 = slot_src[j + 4], s5 = slot_src[j + 5];
    int s6 = slot_src[j + 6], s7 = slot_src[j + 7];
    float w0 = slot_w[j + 0], w1 = slot_w[j + 1];
    float w2 = slot_w[j + 2], w3 = slot_w[j + 3];
    float w4 = slot_w[j + 4], w5 = slot_w[j + 5];
    float w6 = slot_w[j + 6], w7 = slot_w[j + 7];
    float h0 = __half2float(h[(size_t)s0 * 64 + lane]);
    float h1 = __half2float(h[(size_t)s1 * 64 + lane]);
    float h2 = __half2float(h[(size_t)s2 * 64 + lane]);
    float h3 = __half2float(h[(size_t)s3 * 64 + lane]);
    float h4 = __half2float(h[(size_t)s4 * 64 + lane]);
    float h5 = __half2float(h[(size_t)s5 * 64 + lane]);
    float h6 = __half2float(h[(size_t)s6 * 64 + lane]);
    float h7 = __half2float(h[(size_t)s7 * 64 + lane]);
    a0 += w0 * h0;
    c0 += w1 * h1;
    a0 += w2 * h2;
    c0 += w3 * h3;
    a0 += w4 * h4;
    c0 += w5 * h5;
    a0 += w6 * h6;
    c0 += w7 * h7;
  }
  for (; j + 4 <= end; j += 4) {
    int s0 = slot_src[j + 0], s1 = slot_src[j + 1];
    int s2 = slot_src[j + 2], s3 = slot_src[j + 3];
    float w0 = slot_w[j + 0], w1 = slot_w[j + 1];
    float w2 = slot_w[j + 2], w3 = slot_w[j + 3];
    float h0 = __half2float(h[(size_t)s0 * 64 + lane]);
    float h1 = __half2float(h[(size_t)s1 * 64 + lane]);
    float h2 = __half2float(h[(size_t)s2 * 64 + lane]);
    float h3 = __half2float(h[(size_t)s3 * 64 + lane]);
    a0 += w0 * h0;
    c0 += w1 * h1;
    a0 += w2 * h2;
    c0 += w3 * h3;
  }
  for (; j < end; ++j) {
    a0 += slot_w[j] * __half2float(h[(size_t)slot_src[j] * 64 + lane]);
  }
  a0 += c0;
  float di = dinv[w];
  a0 += di * di * __half2float(h[(size_t)w * 64 + lane]);
  if (bias) a0 += bias[lane];
  if (leaky) a0 = (a0 >= 0.f) ? a0 : NEG_SLOPE * a0;
  out[(size_t)w * 64 + lane] = a0;
  if (out16) out16[(size_t)w * 64 + lane] = __float2half(a0);
}

// ============================ launcher ============================

extern "C" void kernel_launch(void* const* d_in, const int* in_sizes, int n_in,
                              void* d_out, int out_size, void* d_ws, size_t ws_size,
                              hipStream_t stream) {
  const float* x   = (const float*)d_in[0];
  const int* eidx  = (const int*)d_in[1];
  const float* W1  = (const float*)d_in[2];
  const float* b1  = (const float*)d_in[3];
  const float* W2  = (const float*)d_in[4];
  const float* b2  = (const float*)d_in[5];
  const float* W3  = (const float*)d_in[6];
  const float* b3  = (const float*)d_in[7];
  const float* W4  = (const float*)d_in[8];
  const float* b4  = (const float*)d_in[9];
  const float* W5  = (const float*)d_in[10];
  const float* b5  = (const float*)d_in[11];
  const float* Wd  = (const float*)d_in[12];
  const float* bd  = (const float*)d_in[13];

  const int N = in_sizes[0] / 128;  // 50000
  const int E = in_sizes[1] / 2;    // 800000
  const int* srcA = eidx;           // edge_index[0]
  const int* dstA = eidx + E;       // edge_index[1]

  // workspace carve-up (256B aligned slots)
  char* ws = (char*)d_ws;
  size_t off = 0;
  auto carve = [&](size_t bytes) {
    char* p = ws + off;
    off = (off + bytes + 255) & ~(size_t)255;
    return p;
  };
  int*   cnt      = (int*)carve((size_t)N * 4);
  int*   rowptr   = (int*)carve((size_t)(N + 1) * 4);
  int*   cursor   = (int*)carve((size_t)N * 4);
  int*   local    = (int*)carve((size_t)N * 4);
  int*   bsum     = (int*)carve(64 * 4);
  int*   bofs     = (int*)carve(64 * 4);
  float* dinv     = (float*)carve((size_t)N * 4);
  int*   slot_src = (int*)carve((size_t)E * 4);
  float* slot_w   = (float*)carve((size_t)E * 4);
  float* bufA     = (float*)carve((size_t)N * 128 * 4);
  float* bufB     = (float*)carve((size_t)N * 128 * 4);
  float* bufC     = (float*)carve((size_t)N * 128 * 4);

  // fp16 views inside bufA: h16 at front (<= N*128 halfs = N*256 B);
  // z16 at byte offset N*256 (N*64 halfs = N*128 B) — disjoint from layer-4 h16.
  __half* h16 = (__half*)bufA;
  __half* z16 = (__half*)((char*)bufA + (size_t)N * 256);

  float* recon = (float*)d_out;                    // [N,128]
  float* zout  = (float*)d_out + (size_t)N * 128;  // [N,64]

  const int nb = (N + 1023) / 1024;  // scan blocks (<=64)
  dim3 b256(256);

  // ---- CSR build (edge structure is layer-invariant) ----
  hipMemsetAsync(cnt, 0, (size_t)N * 4, stream);
  hipMemsetAsync(cursor, 0, (size_t)N * 4, stream);
  k_count<<<(E + 255) / 256, b256, 0, stream>>>(dstA, cnt, E);
  k_dinv<<<(N + 255) / 256, b256, 0, stream>>>(cnt, dinv, N);
  k_scan1<<<nb, b256, 0, stream>>>(cnt, local, bsum, N);
  k_scan2<<<1, 64, 0, stream>>>(bsum, bofs, nb);
  k_scan3<<<(N + 255) / 256, b256, 0, stream>>>(local, bofs, rowptr, N);
  k_fill<<<(E + 255) / 256, b256, 0, stream>>>(srcA, dstA, rowptr, cursor, slot_src,
                                               slot_w, dinv, E);

  const int rowBlocks = (N + BM - 1) / BM;        // 782
  const int aggBlocks = (N * 64 + 255) / 256;     // wave per node
  dim3 g128(128 / BN, rowBlocks);                 // (2, 782)
  dim3 g64(64 / BN, rowBlocks);                   // (1, 782)

  // ---- layer 1: x1 = leaky(gcn(x, W1, b1)) -> bufB ----
  k_sgemm<<<g128, b256, 0, stream>>>(x, W1, nullptr, h16, N, 128, 128, nullptr, 0, nullptr);
  k_agg128<<<aggBlocks, b256, 0, stream>>>(h16, rowptr, slot_src, slot_w, dinv, b1,
                                           nullptr, bufB, N, 1);
  // ---- layer 2: x2 = leaky(gcn(x1, W2, b2)) -> bufC ----
  k_sgemm<<<g128, b256, 0, stream>>>(bufB, W2, nullptr, h16, N, 128, 128, nullptr, 0, nullptr);
  k_agg128<<<aggBlocks, b256, 0, stream>>>(h16, rowptr, slot_src, slot_w, dinv, b2,
                                           nullptr, bufC, N, 1);
  // ---- layer 3: x3 = leaky(gcn(x2, W3, b3)) + x2 -> bufB ----
  k_sgemm<<<g128, b256, 0, stream>>>(bufC, W3, nullptr, h16, N, 128, 128, nullptr, 0, nullptr);
  k_agg128<<<aggBlocks, b256, 0, stream>>>(h16, rowptr, slot_src, slot_w, dinv, b3,
                                           bufC, bufB, N, 1);
  // ---- layer 4: z = gcn(x3, W4, b4) -> zout (fp32 output) + z16 twin ----
  k_sgemm<<<g64, b256, 0, stream>>>(bufB, W4, nullptr, h16, N, 128, 64, nullptr, 0, nullptr);
  k_agg64<<<aggBlocks, b256, 0, stream>>>(h16, rowptr, slot_src, slot_w, dinv, b4,
                                          zout, z16, N, 0);
  // ---- layer 5 (agg-first, linearity): za = agg64(z16) -> bufB; xr = leaky(za@W5+b5) ----
  k_agg64<<<aggBlocks, b256, 0, stream>>>(z16, rowptr, slot_src, slot_w, dinv, nullptr,
                                          bufB, nullptr, N, 0);
  k_sgemm<<<g128, b256, 0, stream>>>(bufB, W5, bufC, nullptr, N, 64, 128, b5, 1, nullptr);
  // ---- decode: recon = xr @ Wd + bd + x ----
  k_sgemm<<<g128, b256, 0, stream>>>(bufC, Wd, recon, nullptr, N, 128, 128, bd, 0, x);
}

// Round 14
// 502.053 us; speedup vs baseline: 1.8235x; 1.0314x over previous
//
#include <hip/hip_runtime.h>
#include <hip/hip_fp16.h>

#define NEG_SLOPE 0.01f

typedef __attribute__((ext_vector_type(4))) _Float16 half4v;
typedef __attribute__((ext_vector_type(8))) _Float16 half8v;
typedef __attribute__((ext_vector_type(4))) float f32x4;

// ============================ CSR build ============================

__global__ __launch_bounds__(256) void k_count(const int* __restrict__ dst,
                                               int* __restrict__ cnt, int E) {
  int e = blockIdx.x * 256 + threadIdx.x;
  if (e < E) atomicAdd(&cnt[dst[e]], 1);
}

__global__ __launch_bounds__(256) void k_dinv(const int* __restrict__ cnt,
                                              float* __restrict__ dinv, int n) {
  int i = blockIdx.x * 256 + threadIdx.x;
  if (i < n) dinv[i] = rsqrtf((float)cnt[i] + 1.0f);
}

// scan over cnt -> exclusive rowptr.  1024 elements per block (256 thr x 4).
__global__ __launch_bounds__(256) void k_scan1(const int* __restrict__ cnt,
                                               int* __restrict__ local,
                                               int* __restrict__ bsum, int n) {
  __shared__ int lds[256];
  int b = blockIdx.x, t = threadIdx.x;
  int base = b * 1024 + t * 4;
  int v0 = (base + 0 < n) ? cnt[base + 0] : 0;
  int v1 = (base + 1 < n) ? cnt[base + 1] : 0;
  int v2 = (base + 2 < n) ? cnt[base + 2] : 0;
  int v3 = (base + 3 < n) ? cnt[base + 3] : 0;
  int s = v0 + v1 + v2 + v3;
  lds[t] = s;
  __syncthreads();
  for (int ofs = 1; ofs < 256; ofs <<= 1) {
    int x = (t >= ofs) ? lds[t - ofs] : 0;
    __syncthreads();
    lds[t] += x;
    __syncthreads();
  }
  int run = lds[t] - s;  // exclusive prefix of this thread's chunk
  run += v0; if (base + 0 < n) local[base + 0] = run;
  run += v1; if (base + 1 < n) local[base + 1] = run;
  run += v2; if (base + 2 < n) local[base + 2] = run;
  run += v3; if (base + 3 < n) local[base + 3] = run;
  if (t == 255) bsum[b] = lds[255];
}

__global__ __launch_bounds__(64) void k_scan2(const int* __restrict__ bsum,
                                              int* __restrict__ bofs, int nb) {
  __shared__ int lds[64];
  int t = threadIdx.x;
  int v = (t < nb) ? bsum[t] : 0;
  lds[t] = v;
  __syncthreads();
  for (int ofs = 1; ofs < 64; ofs <<= 1) {
    int x = (t >= ofs) ? lds[t - ofs] : 0;
    __syncthreads();
    lds[t] += x;
    __syncthreads();
  }
  if (t < nb) bofs[t] = lds[t] - v;
}

__global__ __launch_bounds__(256) void k_scan3(const int* __restrict__ local,
                                               const int* __restrict__ bofs,
                                               int* __restrict__ rowptr, int n) {
  int i = blockIdx.x * 256 + threadIdx.x;
  if (i < n) rowptr[i + 1] = local[i] + bofs[i >> 10];
  if (i == 0) rowptr[0] = 0;
}

// Packed slot: .x = src index, .y = float bits of edge weight.  One 8B random
// write per edge (vs 2x4B to two arrays) -> halves write-allocate lines.
__global__ __launch_bounds__(256) void k_fill(const int* __restrict__ src,
                                              const int* __restrict__ dst,
                                              const int* __restrict__ rowptr,
                                              int* __restrict__ cursor,
                                              int2* __restrict__ slots,
                                              const float* __restrict__ dinv, int E) {
  int e = blockIdx.x * 256 + threadIdx.x;
  if (e < E) {
    int s = src[e], d = dst[e];
    int p = rowptr[d] + atomicAdd(&cursor[d], 1);
    slots[p] = make_int2(s, __float_as_int(dinv[s] * dinv[d]));
  }
}

// ============================ weight prep ============================
// Wt[m][k] = (fp16) W[k][m]  — tiny, once per launch per weight.
__global__ __launch_bounds__(256) void k_wt(const float* __restrict__ W,
                                            _Float16* __restrict__ Wt, int K, int M) {
  int i = blockIdx.x * 256 + threadIdx.x;
  if (i < K * M) {
    int k = i / M, m = i % M;
    Wt[(size_t)m * K + k] = (_Float16)W[(size_t)k * M + m];
  }
}

// ============================ MFMA GEMM ============================
// C[N,M] = A[N,K] @ B[K,M] (+bias) (leaky?) (+addp); K in {64,128}, M = NJ*32.
// A fp32 split into hi+lo fp16 in LDS (fp32-class accuracy); B fp16 [M][K].
// Block: 256 thr = 4 waves (2x2); wave tile 32 x (NJ*16); 16x16x32 f16 MFMA.
// A/B fragments use the SAME slot->k mapping (k = kgroup*8 + i), so the
// result is correct under any internal k-permutation of the instruction.
// C/D layout (HW-verified): col = lane&15, row = (lane>>4)*4 + reg.
template <int NJ>
__global__ __launch_bounds__(256) void k_hgemm(const float* __restrict__ A,
                                               const _Float16* __restrict__ Bt,
                                               float* __restrict__ C,
                                               __half* __restrict__ C16, int N, int K,
                                               int M, const float* __restrict__ bias,
                                               int leaky,
                                               const float* __restrict__ addp) {
  __shared__ _Float16 Ah[64][40];      // 40 = 32 + 8 pad (bank spread)
  __shared__ _Float16 Al[64][40];
  __shared__ _Float16 Bs[NJ * 32][40];
  int t = threadIdx.x;
  int row0 = blockIdx.x * 64;
  int lane = t & 63;
  int wid = t >> 6;
  int wr = wid >> 1, wc = wid & 1;     // 2x2 wave grid
  int l15 = lane & 15, lg = lane >> 4; // fragment row/col & k-group
  f32x4 acc[2][NJ] = {};
  for (int k0 = 0; k0 < K; k0 += 32) {
    __syncthreads();
    // A tile 64 rows x 32 k: 512 float4 loads, hi/lo fp16 split into LDS.
    for (int i = t; i < 512; i += 256) {
      int r = i >> 3, kq = i & 7;
      int gr = row0 + r;
      float4 v = make_float4(0.f, 0.f, 0.f, 0.f);
      if (gr < N) v = *(const float4*)&A[(size_t)gr * K + k0 + kq * 4];
      half4v hi = {(_Float16)v.x, (_Float16)v.y, (_Float16)v.z, (_Float16)v.w};
      half4v lo = {(_Float16)(v.x - (float)hi[0]), (_Float16)(v.y - (float)hi[1]),
                   (_Float16)(v.z - (float)hi[2]), (_Float16)(v.w - (float)hi[3])};
      *(half4v*)&Ah[r][kq * 4] = hi;
      *(half4v*)&Al[r][kq * 4] = lo;
    }
    // B tile (NJ*32 cols) x 32 k from fp16 Bt[M][K]: 16B copies.
    for (int i = t; i < NJ * 32 * 4; i += 256) {
      int c = i >> 2, kg = i & 3;
      *(half8v*)&Bs[c][kg * 8] = *(const half8v*)&Bt[(size_t)c * K + k0 + kg * 8];
    }
    __syncthreads();
    half8v ah0 = *(half8v*)&Ah[wr * 32 + l15][lg * 8];
    half8v ah1 = *(half8v*)&Ah[wr * 32 + 16 + l15][lg * 8];
    half8v al0 = *(half8v*)&Al[wr * 32 + l15][lg * 8];
    half8v al1 = *(half8v*)&Al[wr * 32 + 16 + l15][lg * 8];
#pragma unroll
    for (int nj = 0; nj < NJ; ++nj) {
      half8v bf = *(half8v*)&Bs[wc * (NJ * 16) + nj * 16 + l15][lg * 8];
      acc[0][nj] = __builtin_amdgcn_mfma_f32_16x16x32_f16(ah0, bf, acc[0][nj], 0, 0, 0);
      acc[0][nj] = __builtin_amdgcn_mfma_f32_16x16x32_f16(al0, bf, acc[0][nj], 0, 0, 0);
      acc[1][nj] = __builtin_amdgcn_mfma_f32_16x16x32_f16(ah1, bf, acc[1][nj], 0, 0, 0);
      acc[1][nj] = __builtin_amdgcn_mfma_f32_16x16x32_f16(al1, bf, acc[1][nj], 0, 0, 0);
    }
  }
#pragma unroll
  for (int mi = 0; mi < 2; ++mi) {
#pragma unroll
    for (int nj = 0; nj < NJ; ++nj) {
      int c = wc * (NJ * 16) + nj * 16 + l15;
#pragma unroll
      for (int jj = 0; jj < 4; ++jj) {
        int r = row0 + wr * 32 + mi * 16 + lg * 4 + jj;
        if (r >= N) continue;
        float v = acc[mi][nj][jj];
        if (bias) v += bias[c];
        if (leaky) v = (v >= 0.f) ? v : NEG_SLOPE * v;
        if (addp) v += addp[(size_t)r * M + c];
        if (C16) C16[(size_t)r * M + c] = __float2half(v);
        else C[(size_t)r * M + c] = v;
      }
    }
  }
}

// ============================ Aggregation ============================
// out[d] = sum_{e: dst=d} w_e * h[src_e] + dinv[d]^2 * h[d] (+bias) (leaky?) (+resid)
// h fp16, packed int2 slots, fp32 accumulate, 8-way edge unroll.
__global__ __launch_bounds__(256) void k_agg128(const __half* __restrict__ h,
                                                const int* __restrict__ rowptr,
                                                const int2* __restrict__ slots,
                                                const float* __restrict__ dinv,
                                                const float* __restrict__ bias,
                                                const float* __restrict__ resid,
                                                float* __restrict__ out, int n,
                                                int leaky) {
  int w = (blockIdx.x * 256 + threadIdx.x) >> 6;
  int lane = threadIdx.x & 63;
  if (w >= n) return;
  int beg = rowptr[w], end = rowptr[w + 1];
  float a0 = 0.f, a1 = 0.f, c0 = 0.f, c1 = 0.f;
  int j = beg;
  for (; j + 8 <= end; j += 8) {
    int2 e0 = slots[j + 0], e1 = slots[j + 1], e2 = slots[j + 2], e3 = slots[j + 3];
    int2 e4 = slots[j + 4], e5 = slots[j + 5], e6 = slots[j + 6], e7 = slots[j + 7];
    float2 h0 = __half22float2(*(const __half2*)&h[(size_t)e0.x * 128 + lane * 2]);
    float2 h1 = __half22float2(*(const __half2*)&h[(size_t)e1.x * 128 + lane * 2]);
    float2 h2 = __half22float2(*(const __half2*)&h[(size_t)e2.x * 128 + lane * 2]);
    float2 h3 = __half22float2(*(const __half2*)&h[(size_t)e3.x * 128 + lane * 2]);
    float2 h4 = __half22float2(*(const __half2*)&h[(size_t)e4.x * 128 + lane * 2]);
    float2 h5 = __half22float2(*(const __half2*)&h[(size_t)e5.x * 128 + lane * 2]);
    float2 h6 = __half22float2(*(const __half2*)&h[(size_t)e6.x * 128 + lane * 2]);
    float2 h7 = __half22float2(*(const __half2*)&h[(size_t)e7.x * 128 + lane * 2]);
    float w0 = __int_as_float(e0.y), w1 = __int_as_float(e1.y);
    float w2 = __int_as_float(e2.y), w3 = __int_as_float(e3.y);
    float w4 = __int_as_float(e4.y), w5 = __int_as_float(e5.y);
    float w6 = __int_as_float(e6.y), w7 = __int_as_float(e7.y);
    a0 += w0 * h0.x; a1 += w0 * h0.y;
    c0 += w1 * h1.x; c1 += w1 * h1.y;
    a0 += w2 * h2.x; a1 += w2 * h2.y;
    c0 += w3 * h3.x; c1 += w3 * h3.y;
    a0 += w4 * h4.x; a1 += w4 * h4.y;
    c0 += w5 * h5.x; c1 += w5 * h5.y;
    a0 += w6 * h6.x; a1 += w6 * h6.y;
    c0 += w7 * h7.x; c1 += w7 * h7.y;
  }
  for (; j < end; ++j) {
    int2 ee = slots[j];
    float wt = __int_as_float(ee.y);
    float2 hv = __half22float2(*(const __half2*)&h[(size_t)ee.x * 128 + lane * 2]);
    a0 += wt * hv.x;
    a1 += wt * hv.y;
  }
  a0 += c0; a1 += c1;
  float di = dinv[w];
  float sw = di * di;
  float2 hs = __half22float2(*(const __half2*)&h[(size_t)w * 128 + lane * 2]);
  a0 += sw * hs.x;
  a1 += sw * hs.y;
  if (bias) {
    a0 += bias[lane * 2];
    a1 += bias[lane * 2 + 1];
  }
  if (leaky) {
    a0 = (a0 >= 0.f) ? a0 : NEG_SLOPE * a0;
    a1 = (a1 >= 0.f) ? a1 : NEG_SLOPE * a1;
  }
  if (resid) {
    float2 rv = *(const float2*)&resid[(size_t)w * 128 + lane * 2];
    a0 += rv.x;
    a1 += rv.y;
  }
  *(float2*)&out[(size_t)w * 128 + lane * 2] = make_float2(a0, a1);
}

// 64-dim variant (lane covers col = lane), fp16 gather, packed slots.
__global__ __launch_bounds__(256) void k_agg64(const __half* __restrict__ h,
                                               const int* __restrict__ rowptr,
                                               const int2* __restrict__ slots,
                                               const float* __restrict__ dinv,
                                               const float* __restrict__ bias,
                                               float* __restrict__ out,
                                               __half* __restrict__ out16, int n,
                                               int leaky) {
  int w = (blockIdx.x * 256 + threadIdx.x) >> 6;
  int lane = threadIdx.x & 63;
  if (w >= n) return;
  int beg = rowptr[w], end = rowptr[w + 1];
  float a0 = 0.f, c0 = 0.f;
  int j = beg;
  for (; j + 8 <= end; j += 8) {
    int2 e0 = slots[j + 0], e1 = slots[j + 1], e2 = slots[j + 2], e3 = slots[j + 3];
    int2 e4 = slots[j + 4], e5 = slots[j + 5], e6 = slots[j + 6], e7 = slots[j + 7];
    float h0 = __half2float(h[(size_t)e0.x * 64 + lane]);
    float h1 = __half2float(h[(size_t)e1.x * 64 + lane]);
    float h2 = __half2float(h[(size_t)e2.x * 64 + lane]);
    float h3 = __half2float(h[(size_t)e3.x * 64 + lane]);
    float h4 = __half2float(h[(size_t)e4.x * 64 + lane]);
    float h5 = __half2float(h[(size_t)e5.x * 64 + lane]);
    float h6 = __half2float(h[(size_t)e6.x * 64 + lane]);
    float h7 = __half2float(h[(size_t)e7.x * 64 + lane]);
    a0 += __int_as_float(e0.y) * h0;
    c0 += __int_as_float(e1.y) * h1;
    a0 += __int_as_float(e2.y) * h2;
    c0 += __int_as_float(e3.y) * h3;
    a0 += __int_as_float(e4.y) * h4;
    c0 += __int_as_float(e5.y) * h5;
    a0 += __int_as_float(e6.y) * h6;
    c0 += __int_as_float(e7.y) * h7;
  }
  for (; j < end; ++j) {
    int2 ee = slots[j];
    a0 += __int_as_float(ee.y) * __half2float(h[(size_t)ee.x * 64 + lane]);
  }
  a0 += c0;
  float di = dinv[w];
  a0 += di * di * __half2float(h[(size_t)w * 64 + lane]);
  if (bias) a0 += bias[lane];
  if (leaky) a0 = (a0 >= 0.f) ? a0 : NEG_SLOPE * a0;
  out[(size_t)w * 64 + lane] = a0;
  if (out16) out16[(size_t)w * 64 + lane] = __float2half(a0);
}

// ============================ launcher ============================

extern "C" void kernel_launch(void* const* d_in, const int* in_sizes, int n_in,
                              void* d_out, int out_size, void* d_ws, size_t ws_size,
                              hipStream_t stream) {
  const float* x   = (const float*)d_in[0];
  const int* eidx  = (const int*)d_in[1];
  const float* W1  = (const float*)d_in[2];
  const float* b1  = (const float*)d_in[3];
  const float* W2  = (const float*)d_in[4];
  const float* b2  = (const float*)d_in[5];
  const float* W3  = (const float*)d_in[6];
  const float* b3  = (const float*)d_in[7];
  const float* W4  = (const float*)d_in[8];
  const float* b4  = (const float*)d_in[9];
  const float* W5  = (const float*)d_in[10];
  const float* b5  = (const float*)d_in[11];
  const float* Wd  = (const float*)d_in[12];
  const float* bd  = (const float*)d_in[13];

  const int N = in_sizes[0] / 128;  // 50000
  const int E = in_sizes[1] / 2;    // 800000
  const int* srcA = eidx;           // edge_index[0]
  const int* dstA = eidx + E;       // edge_index[1]

  // workspace carve-up (256B aligned slots)
  char* ws = (char*)d_ws;
  size_t off = 0;
  auto carve = [&](size_t bytes) {
    char* p = ws + off;
    off = (off + bytes + 255) & ~(size_t)255;
    return p;
  };
  int*   cnt      = (int*)carve((size_t)N * 4);
  int*   rowptr   = (int*)carve((size_t)(N + 1) * 4);
  int*   cursor   = (int*)carve((size_t)N * 4);
  int*   local    = (int*)carve((size_t)N * 4);
  int*   bsum     = (int*)carve(64 * 4);
  int*   bofs     = (int*)carve(64 * 4);
  float* dinv     = (float*)carve((size_t)N * 4);
  int2*  slots    = (int2*)carve((size_t)E * 8);
  float* bufA     = (float*)carve((size_t)N * 128 * 4);
  float* bufB     = (float*)carve((size_t)N * 128 * 4);
  float* bufC     = (float*)carve((size_t)N * 128 * 4);
  _Float16* Wt1   = (_Float16*)carve(128 * 128 * 2);
  _Float16* Wt2   = (_Float16*)carve(128 * 128 * 2);
  _Float16* Wt3   = (_Float16*)carve(128 * 128 * 2);
  _Float16* Wt4   = (_Float16*)carve(128 * 64 * 2);
  _Float16* Wt5   = (_Float16*)carve(64 * 128 * 2);
  _Float16* Wtd   = (_Float16*)carve(128 * 128 * 2);

  // fp16 views inside bufA: h16 at front; z16 at byte offset N*256 (disjoint).
  __half* h16 = (__half*)bufA;
  __half* z16 = (__half*)((char*)bufA + (size_t)N * 256);

  float* recon = (float*)d_out;                    // [N,128]
  float* zout  = (float*)d_out + (size_t)N * 128;  // [N,64]

  const int nb = (N + 1023) / 1024;  // scan blocks (<=64)
  dim3 b256(256);

  // ---- CSR build (edge structure is layer-invariant) ----
  hipMemsetAsync(cnt, 0, (size_t)N * 4, stream);
  hipMemsetAsync(cursor, 0, (size_t)N * 4, stream);
  k_count<<<(E + 255) / 256, b256, 0, stream>>>(dstA, cnt, E);
  k_dinv<<<(N + 255) / 256, b256, 0, stream>>>(cnt, dinv, N);
  k_scan1<<<nb, b256, 0, stream>>>(cnt, local, bsum, N);
  k_scan2<<<1, 64, 0, stream>>>(bsum, bofs, nb);
  k_scan3<<<(N + 255) / 256, b256, 0, stream>>>(local, bofs, rowptr, N);
  k_fill<<<(E + 255) / 256, b256, 0, stream>>>(srcA, dstA, rowptr, cursor, slots,
                                               dinv, E);

  // ---- weight fp16 transposes (tiny) ----
  k_wt<<<(128 * 128 + 255) / 256, b256, 0, stream>>>(W1, Wt1, 128, 128);
  k_wt<<<(128 * 128 + 255) / 256, b256, 0, stream>>>(W2, Wt2, 128, 128);
  k_wt<<<(128 * 128 + 255) / 256, b256, 0, stream>>>(W3, Wt3, 128, 128);
  k_wt<<<(128 * 64 + 255) / 256, b256, 0, stream>>>(W4, Wt4, 128, 64);
  k_wt<<<(64 * 128 + 255) / 256, b256, 0, stream>>>(W5, Wt5, 64, 128);
  k_wt<<<(128 * 128 + 255) / 256, b256, 0, stream>>>(Wd, Wtd, 128, 128);

  const int gemmBlocks = (N + 63) / 64;          // 782
  const int aggBlocks  = (N * 64 + 255) / 256;   // wave per node

  // ---- layer 1: x1 = leaky(gcn(x, W1, b1)) -> bufB ----
  k_hgemm<4><<<gemmBlocks, b256, 0, stream>>>(x, Wt1, nullptr, h16, N, 128, 128,
                                              nullptr, 0, nullptr);
  k_agg128<<<aggBlocks, b256, 0, stream>>>(h16, rowptr, slots, dinv, b1, nullptr,
                                           bufB, N, 1);
  // ---- layer 2: x2 = leaky(gcn(x1, W2, b2)) -> bufC ----
  k_hgemm<4><<<gemmBlocks, b256, 0, stream>>>(bufB, Wt2, nullptr, h16, N, 128, 128,
                                              nullptr, 0, nullptr);
  k_agg128<<<aggBlocks, b256, 0, stream>>>(h16, rowptr, slots, dinv, b2, nullptr,
                                           bufC, N, 1);
  // ---- layer 3: x3 = leaky(gcn(x2, W3, b3)) + x2 -> bufB ----
  k_hgemm<4><<<gemmBlocks, b256, 0, stream>>>(bufC, Wt3, nullptr, h16, N, 128, 128,
                                              nullptr, 0, nullptr);
  k_agg128<<<aggBlocks, b256, 0, stream>>>(h16, rowptr, slots, dinv, b3, bufC,
                                           bufB, N, 1);
  // ---- layer 4: z = gcn(x3, W4, b4) -> zout (fp32) + z16 twin ----
  k_hgemm<2><<<gemmBlocks, b256, 0, stream>>>(bufB, Wt4, nullptr, h16, N, 128, 64,
                                              nullptr, 0, nullptr);
  k_agg64<<<aggBlocks, b256, 0, stream>>>(h16, rowptr, slots, dinv, b4, zout, z16,
                                          N, 0);
  // ---- layer 5 (agg-first, linearity): za = agg64(z16) -> bufB; xr = leaky(za@W5+b5) ----
  k_agg64<<<aggBlocks, b256, 0, stream>>>(z16, rowptr, slots, dinv, nullptr, bufB,
                                          nullptr, N, 0);
  k_hgemm<4><<<gemmBlocks, b256, 0, stream>>>(bufB, Wt5, bufC, nullptr, N, 64, 128,
                                              b5, 1, nullptr);
  // ---- decode: recon = xr @ Wd + bd + x ----
  k_hgemm<4><<<gemmBlocks, b256, 0, stream>>>(bufC, Wtd, recon, nullptr, N, 128, 128,
                                              bd, 0, x);
}

// Round 15
// 467.831 us; speedup vs baseline: 1.9569x; 1.0731x over previous
//
#include <hip/hip_runtime.h>
#include <hip/hip_fp16.h>

#define NEG_SLOPE 0.01f

typedef __attribute__((ext_vector_type(4))) _Float16 half4v;
typedef __attribute__((ext_vector_type(8))) _Float16 half8v;
typedef __attribute__((ext_vector_type(4))) float f32x4;

// ============================ CSR build ============================

__global__ __launch_bounds__(256) void k_count(const int* __restrict__ dst,
                                               int* __restrict__ cnt, int E) {
  int e = blockIdx.x * 256 + threadIdx.x;
  if (e < E) atomicAdd(&cnt[dst[e]], 1);
}

__global__ __launch_bounds__(256) void k_dinv(const int* __restrict__ cnt,
                                              float* __restrict__ dinv, int n) {
  int i = blockIdx.x * 256 + threadIdx.x;
  if (i < n) dinv[i] = rsqrtf((float)cnt[i] + 1.0f);
}

// scan over cnt -> exclusive rowptr.  1024 elements per block (256 thr x 4).
__global__ __launch_bounds__(256) void k_scan1(const int* __restrict__ cnt,
                                               int* __restrict__ local,
                                               int* __restrict__ bsum, int n) {
  __shared__ int lds[256];
  int b = blockIdx.x, t = threadIdx.x;
  int base = b * 1024 + t * 4;
  int v0 = (base + 0 < n) ? cnt[base + 0] : 0;
  int v1 = (base + 1 < n) ? cnt[base + 1] : 0;
  int v2 = (base + 2 < n) ? cnt[base + 2] : 0;
  int v3 = (base + 3 < n) ? cnt[base + 3] : 0;
  int s = v0 + v1 + v2 + v3;
  lds[t] = s;
  __syncthreads();
  for (int ofs = 1; ofs < 256; ofs <<= 1) {
    int x = (t >= ofs) ? lds[t - ofs] : 0;
    __syncthreads();
    lds[t] += x;
    __syncthreads();
  }
  int run = lds[t] - s;  // exclusive prefix of this thread's chunk
  run += v0; if (base + 0 < n) local[base + 0] = run;
  run += v1; if (base + 1 < n) local[base + 1] = run;
  run += v2; if (base + 2 < n) local[base + 2] = run;
  run += v3; if (base + 3 < n) local[base + 3] = run;
  if (t == 255) bsum[b] = lds[255];
}

__global__ __launch_bounds__(64) void k_scan2(const int* __restrict__ bsum,
                                              int* __restrict__ bofs, int nb) {
  __shared__ int lds[64];
  int t = threadIdx.x;
  int v = (t < nb) ? bsum[t] : 0;
  lds[t] = v;
  __syncthreads();
  for (int ofs = 1; ofs < 64; ofs <<= 1) {
    int x = (t >= ofs) ? lds[t - ofs] : 0;
    __syncthreads();
    lds[t] += x;
    __syncthreads();
  }
  if (t < nb) bofs[t] = lds[t] - v;
}

__global__ __launch_bounds__(256) void k_scan3(const int* __restrict__ local,
                                               const int* __restrict__ bofs,
                                               int* __restrict__ rowptr, int n) {
  int i = blockIdx.x * 256 + threadIdx.x;
  if (i < n) rowptr[i + 1] = local[i] + bofs[i >> 10];
  if (i == 0) rowptr[0] = 0;
}

// Packed slot: .x = src index, .y = float bits of edge weight.
__global__ __launch_bounds__(256) void k_fill(const int* __restrict__ src,
                                              const int* __restrict__ dst,
                                              const int* __restrict__ rowptr,
                                              int* __restrict__ cursor,
                                              int2* __restrict__ slots,
                                              const float* __restrict__ dinv, int E) {
  int e = blockIdx.x * 256 + threadIdx.x;
  if (e < E) {
    int s = src[e], d = dst[e];
    int p = rowptr[d] + atomicAdd(&cursor[d], 1);
    slots[p] = make_int2(s, __float_as_int(dinv[s] * dinv[d]));
  }
}

// ============================ weight prep ============================
// Wt[m][k] = (fp16) W[k][m]  — tiny, once per launch per weight.
__global__ __launch_bounds__(256) void k_wt(const float* __restrict__ W,
                                            _Float16* __restrict__ Wt, int K, int M) {
  int i = blockIdx.x * 256 + threadIdx.x;
  if (i < K * M) {
    int k = i / M, m = i % M;
    Wt[(size_t)m * K + k] = (_Float16)W[(size_t)k * M + m];
  }
}

// ============================ MFMA GEMM ============================
// C[N,M] = A[N,K] @ B[K,M] (+bias) (leaky?) (+addp); K in {64,128}, M = NJ*32.
// A fp32 split into hi+lo fp16 in LDS (fp32-class accuracy); B fp16 [M][K].
// Block: 256 thr = 4 waves (2x2); wave tile 32 x (NJ*16); 16x16x32 f16 MFMA.
// C/D layout (HW-verified): col = lane&15, row = (lane>>4)*4 + reg.
template <int NJ>
__global__ __launch_bounds__(256) void k_hgemm(const float* __restrict__ A,
                                               const _Float16* __restrict__ Bt,
                                               float* __restrict__ C,
                                               __half* __restrict__ C16, int N, int K,
                                               int M, const float* __restrict__ bias,
                                               int leaky,
                                               const float* __restrict__ addp) {
  __shared__ _Float16 Ah[64][40];      // 40 = 32 + 8 pad (bank spread)
  __shared__ _Float16 Al[64][40];
  __shared__ _Float16 Bs[NJ * 32][40];
  int t = threadIdx.x;
  int row0 = blockIdx.x * 64;
  int lane = t & 63;
  int wid = t >> 6;
  int wr = wid >> 1, wc = wid & 1;     // 2x2 wave grid
  int l15 = lane & 15, lg = lane >> 4; // fragment row/col & k-group
  f32x4 acc[2][NJ] = {};
  for (int k0 = 0; k0 < K; k0 += 32) {
    __syncthreads();
    // A tile 64 rows x 32 k: 512 float4 loads, hi/lo fp16 split into LDS.
    for (int i = t; i < 512; i += 256) {
      int r = i >> 3, kq = i & 7;
      int gr = row0 + r;
      float4 v = make_float4(0.f, 0.f, 0.f, 0.f);
      if (gr < N) v = *(const float4*)&A[(size_t)gr * K + k0 + kq * 4];
      half4v hi = {(_Float16)v.x, (_Float16)v.y, (_Float16)v.z, (_Float16)v.w};
      half4v lo = {(_Float16)(v.x - (float)hi[0]), (_Float16)(v.y - (float)hi[1]),
                   (_Float16)(v.z - (float)hi[2]), (_Float16)(v.w - (float)hi[3])};
      *(half4v*)&Ah[r][kq * 4] = hi;
      *(half4v*)&Al[r][kq * 4] = lo;
    }
    // B tile (NJ*32 cols) x 32 k from fp16 Bt[M][K]: 16B copies.
    for (int i = t; i < NJ * 32 * 4; i += 256) {
      int c = i >> 2, kg = i & 3;
      *(half8v*)&Bs[c][kg * 8] = *(const half8v*)&Bt[(size_t)c * K + k0 + kg * 8];
    }
    __syncthreads();
    half8v ah0 = *(half8v*)&Ah[wr * 32 + l15][lg * 8];
    half8v ah1 = *(half8v*)&Ah[wr * 32 + 16 + l15][lg * 8];
    half8v al0 = *(half8v*)&Al[wr * 32 + l15][lg * 8];
    half8v al1 = *(half8v*)&Al[wr * 32 + 16 + l15][lg * 8];
#pragma unroll
    for (int nj = 0; nj < NJ; ++nj) {
      half8v bf = *(half8v*)&Bs[wc * (NJ * 16) + nj * 16 + l15][lg * 8];
      acc[0][nj] = __builtin_amdgcn_mfma_f32_16x16x32_f16(ah0, bf, acc[0][nj], 0, 0, 0);
      acc[0][nj] = __builtin_amdgcn_mfma_f32_16x16x32_f16(al0, bf, acc[0][nj], 0, 0, 0);
      acc[1][nj] = __builtin_amdgcn_mfma_f32_16x16x32_f16(ah1, bf, acc[1][nj], 0, 0, 0);
      acc[1][nj] = __builtin_amdgcn_mfma_f32_16x16x32_f16(al1, bf, acc[1][nj], 0, 0, 0);
    }
  }
#pragma unroll
  for (int mi = 0; mi < 2; ++mi) {
#pragma unroll
    for (int nj = 0; nj < NJ; ++nj) {
      int c = wc * (NJ * 16) + nj * 16 + l15;
#pragma unroll
      for (int jj = 0; jj < 4; ++jj) {
        int r = row0 + wr * 32 + mi * 16 + lg * 4 + jj;
        if (r >= N) continue;
        float v = acc[mi][nj][jj];
        if (bias) v += bias[c];
        if (leaky) v = (v >= 0.f) ? v : NEG_SLOPE * v;
        if (addp) v += addp[(size_t)r * M + c];
        if (C16) C16[(size_t)r * M + c] = __float2half(v);
        else C[(size_t)r * M + c] = v;
      }
    }
  }
}

// ============================ Aggregation ============================
// out[d] = sum_{e: dst=d} w_e * h[src_e] + dinv[d]^2 * h[d] (+bias) (leaky?) (+resid)
// Wide-gather layout: each HALF-WAVE (32 lanes x 8B half4) covers one full
// 256B row; the two halves process different edges in the same instruction
// (stride-2 chains), halving VMEM instruction count.  Cross-half shfl_xor(32)
// reduce; lanes 0-31 do epilogue + float4 store.
__global__ __launch_bounds__(256) void k_agg128(const __half* __restrict__ h,
                                                const int* __restrict__ rowptr,
                                                const int2* __restrict__ slots,
                                                const float* __restrict__ dinv,
                                                const float* __restrict__ bias,
                                                const float* __restrict__ resid,
                                                float* __restrict__ out, int n,
                                                int leaky) {
  int w = (blockIdx.x * 256 + threadIdx.x) >> 6;
  int lane = threadIdx.x & 63;
  if (w >= n) return;
  int hf = lane >> 5, sl = lane & 31;  // half id, sub-lane; cols sl*4..sl*4+3
  int beg = rowptr[w], end = rowptr[w + 1];
  float a0 = 0.f, a1 = 0.f, a2 = 0.f, a3 = 0.f;
  float c0 = 0.f, c1 = 0.f, c2 = 0.f, c3 = 0.f;
  int jj = beg + hf;
  // 4 edges per half per iteration (8 edges/wave-iter), stride-2 chains.
  for (; jj + 6 < end; jj += 8) {
    int2 e0 = slots[jj], e1 = slots[jj + 2], e2 = slots[jj + 4], e3 = slots[jj + 6];
    half4v v0 = *(const half4v*)&h[(size_t)e0.x * 128 + sl * 4];
    half4v v1 = *(const half4v*)&h[(size_t)e1.x * 128 + sl * 4];
    half4v v2 = *(const half4v*)&h[(size_t)e2.x * 128 + sl * 4];
    half4v v3 = *(const half4v*)&h[(size_t)e3.x * 128 + sl * 4];
    float w0 = __int_as_float(e0.y), w1 = __int_as_float(e1.y);
    float w2 = __int_as_float(e2.y), w3 = __int_as_float(e3.y);
    a0 += w0 * (float)v0[0]; a1 += w0 * (float)v0[1];
    a2 += w0 * (float)v0[2]; a3 += w0 * (float)v0[3];
    c0 += w1 * (float)v1[0]; c1 += w1 * (float)v1[1];
    c2 += w1 * (float)v1[2]; c3 += w1 * (float)v1[3];
    a0 += w2 * (float)v2[0]; a1 += w2 * (float)v2[1];
    a2 += w2 * (float)v2[2]; a3 += w2 * (float)v2[3];
    c0 += w3 * (float)v3[0]; c1 += w3 * (float)v3[1];
    c2 += w3 * (float)v3[2]; c3 += w3 * (float)v3[3];
  }
  for (; jj < end; jj += 2) {
    int2 e = slots[jj];
    half4v v = *(const half4v*)&h[(size_t)e.x * 128 + sl * 4];
    float wt = __int_as_float(e.y);
    a0 += wt * (float)v[0]; a1 += wt * (float)v[1];
    a2 += wt * (float)v[2]; a3 += wt * (float)v[3];
  }
  a0 += c0; a1 += c1; a2 += c2; a3 += c3;
  // combine the two halves (each summed a disjoint edge subset)
  a0 += __shfl_xor(a0, 32);
  a1 += __shfl_xor(a1, 32);
  a2 += __shfl_xor(a2, 32);
  a3 += __shfl_xor(a3, 32);
  if (hf == 0) {
    float di = dinv[w];
    float sw = di * di;
    half4v hs = *(const half4v*)&h[(size_t)w * 128 + sl * 4];
    a0 += sw * (float)hs[0]; a1 += sw * (float)hs[1];
    a2 += sw * (float)hs[2]; a3 += sw * (float)hs[3];
    if (bias) {
      a0 += bias[sl * 4 + 0]; a1 += bias[sl * 4 + 1];
      a2 += bias[sl * 4 + 2]; a3 += bias[sl * 4 + 3];
    }
    if (leaky) {
      a0 = (a0 >= 0.f) ? a0 : NEG_SLOPE * a0;
      a1 = (a1 >= 0.f) ? a1 : NEG_SLOPE * a1;
      a2 = (a2 >= 0.f) ? a2 : NEG_SLOPE * a2;
      a3 = (a3 >= 0.f) ? a3 : NEG_SLOPE * a3;
    }
    if (resid) {
      float4 rv = *(const float4*)&resid[(size_t)w * 128 + sl * 4];
      a0 += rv.x; a1 += rv.y; a2 += rv.z; a3 += rv.w;
    }
    *(float4*)&out[(size_t)w * 128 + sl * 4] = make_float4(a0, a1, a2, a3);
  }
}

// 64-dim variant: each QUARTER-WAVE (16 lanes x 8B half4) covers a 128B row;
// 4 edges per instruction (stride-4 chains).  shfl_xor(16)+(32) reduce;
// lanes 0-15 write float4 (+ optional half4 twin).
__global__ __launch_bounds__(256) void k_agg64(const __half* __restrict__ h,
                                               const int* __restrict__ rowptr,
                                               const int2* __restrict__ slots,
                                               const float* __restrict__ dinv,
                                               const float* __restrict__ bias,
                                               float* __restrict__ out,
                                               __half* __restrict__ out16, int n,
                                               int leaky) {
  int w = (blockIdx.x * 256 + threadIdx.x) >> 6;
  int lane = threadIdx.x & 63;
  if (w >= n) return;
  int q = lane >> 4, sl = lane & 15;  // quarter id, sub-lane; cols sl*4..sl*4+3
  int beg = rowptr[w], end = rowptr[w + 1];
  float a0 = 0.f, a1 = 0.f, a2 = 0.f, a3 = 0.f;
  float c0 = 0.f, c1 = 0.f, c2 = 0.f, c3 = 0.f;
  int jj = beg + q;
  // 2 edges per quarter per iteration (8 edges/wave-iter), stride-4 chains.
  for (; jj + 4 < end; jj += 8) {
    int2 e0 = slots[jj], e1 = slots[jj + 4];
    half4v v0 = *(const half4v*)&h[(size_t)e0.x * 64 + sl * 4];
    half4v v1 = *(const half4v*)&h[(size_t)e1.x * 64 + sl * 4];
    float w0 = __int_as_float(e0.y), w1 = __int_as_float(e1.y);
    a0 += w0 * (float)v0[0]; a1 += w0 * (float)v0[1];
    a2 += w0 * (float)v0[2]; a3 += w0 * (float)v0[3];
    c0 += w1 * (float)v1[0]; c1 += w1 * (float)v1[1];
    c2 += w1 * (float)v1[2]; c3 += w1 * (float)v1[3];
  }
  for (; jj < end; jj += 4) {
    int2 e = slots[jj];
    half4v v = *(const half4v*)&h[(size_t)e.x * 64 + sl * 4];
    float wt = __int_as_float(e.y);
    a0 += wt * (float)v[0]; a1 += wt * (float)v[1];
    a2 += wt * (float)v[2]; a3 += wt * (float)v[3];
  }
  a0 += c0; a1 += c1; a2 += c2; a3 += c3;
  a0 += __shfl_xor(a0, 16); a0 += __shfl_xor(a0, 32);
  a1 += __shfl_xor(a1, 16); a1 += __shfl_xor(a1, 32);
  a2 += __shfl_xor(a2, 16); a2 += __shfl_xor(a2, 32);
  a3 += __shfl_xor(a3, 16); a3 += __shfl_xor(a3, 32);
  if (lane < 16) {
    float di = dinv[w];
    float sw = di * di;
    half4v hs = *(const half4v*)&h[(size_t)w * 64 + sl * 4];
    a0 += sw * (float)hs[0]; a1 += sw * (float)hs[1];
    a2 += sw * (float)hs[2]; a3 += sw * (float)hs[3];
    if (bias) {
      a0 += bias[sl * 4 + 0]; a1 += bias[sl * 4 + 1];
      a2 += bias[sl * 4 + 2]; a3 += bias[sl * 4 + 3];
    }
    if (leaky) {
      a0 = (a0 >= 0.f) ? a0 : NEG_SLOPE * a0;
      a1 = (a1 >= 0.f) ? a1 : NEG_SLOPE * a1;
      a2 = (a2 >= 0.f) ? a2 : NEG_SLOPE * a2;
      a3 = (a3 >= 0.f) ? a3 : NEG_SLOPE * a3;
    }
    *(float4*)&out[(size_t)w * 64 + sl * 4] = make_float4(a0, a1, a2, a3);
    if (out16) {
      half4v hv = {(_Float16)a0, (_Float16)a1, (_Float16)a2, (_Float16)a3};
      *(half4v*)&out16[(size_t)w * 64 + sl * 4] = hv;
    }
  }
}

// ============================ launcher ============================

extern "C" void kernel_launch(void* const* d_in, const int* in_sizes, int n_in,
                              void* d_out, int out_size, void* d_ws, size_t ws_size,
                              hipStream_t stream) {
  const float* x   = (const float*)d_in[0];
  const int* eidx  = (const int*)d_in[1];
  const float* W1  = (const float*)d_in[2];
  const float* b1  = (const float*)d_in[3];
  const float* W2  = (const float*)d_in[4];
  const float* b2  = (const float*)d_in[5];
  const float* W3  = (const float*)d_in[6];
  const float* b3  = (const float*)d_in[7];
  const float* W4  = (const float*)d_in[8];
  const float* b4  = (const float*)d_in[9];
  const float* W5  = (const float*)d_in[10];
  const float* b5  = (const float*)d_in[11];
  const float* Wd  = (const float*)d_in[12];
  const float* bd  = (const float*)d_in[13];

  const int N = in_sizes[0] / 128;  // 50000
  const int E = in_sizes[1] / 2;    // 800000
  const int* srcA = eidx;           // edge_index[0]
  const int* dstA = eidx + E;       // edge_index[1]

  // workspace carve-up (256B aligned slots)
  char* ws = (char*)d_ws;
  size_t off = 0;
  auto carve = [&](size_t bytes) {
    char* p = ws + off;
    off = (off + bytes + 255) & ~(size_t)255;
    return p;
  };
  int*   cnt      = (int*)carve((size_t)N * 4);
  int*   rowptr   = (int*)carve((size_t)(N + 1) * 4);
  int*   cursor   = (int*)carve((size_t)N * 4);
  int*   local    = (int*)carve((size_t)N * 4);
  int*   bsum     = (int*)carve(64 * 4);
  int*   bofs     = (int*)carve(64 * 4);
  float* dinv     = (float*)carve((size_t)N * 4);
  int2*  slots    = (int2*)carve((size_t)E * 8);
  float* bufA     = (float*)carve((size_t)N * 128 * 4);
  float* bufB     = (float*)carve((size_t)N * 128 * 4);
  float* bufC     = (float*)carve((size_t)N * 128 * 4);
  _Float16* Wt1   = (_Float16*)carve(128 * 128 * 2);
  _Float16* Wt2   = (_Float16*)carve(128 * 128 * 2);
  _Float16* Wt3   = (_Float16*)carve(128 * 128 * 2);
  _Float16* Wt4   = (_Float16*)carve(128 * 64 * 2);
  _Float16* Wt5   = (_Float16*)carve(64 * 128 * 2);
  _Float16* Wtd   = (_Float16*)carve(128 * 128 * 2);

  // fp16 views inside bufA: h16 at front; z16 at byte offset N*256 (disjoint).
  __half* h16 = (__half*)bufA;
  __half* z16 = (__half*)((char*)bufA + (size_t)N * 256);

  float* recon = (float*)d_out;                    // [N,128]
  float* zout  = (float*)d_out + (size_t)N * 128;  // [N,64]

  const int nb = (N + 1023) / 1024;  // scan blocks (<=64)
  dim3 b256(256);

  // ---- CSR build (edge structure is layer-invariant) ----
  hipMemsetAsync(cnt, 0, (size_t)N * 4, stream);
  hipMemsetAsync(cursor, 0, (size_t)N * 4, stream);
  k_count<<<(E + 255) / 256, b256, 0, stream>>>(dstA, cnt, E);
  k_dinv<<<(N + 255) / 256, b256, 0, stream>>>(cnt, dinv, N);
  k_scan1<<<nb, b256, 0, stream>>>(cnt, local, bsum, N);
  k_scan2<<<1, 64, 0, stream>>>(bsum, bofs, nb);
  k_scan3<<<(N + 255) / 256, b256, 0, stream>>>(local, bofs, rowptr, N);
  k_fill<<<(E + 255) / 256, b256, 0, stream>>>(srcA, dstA, rowptr, cursor, slots,
                                               dinv, E);

  // ---- weight fp16 transposes (tiny) ----
  k_wt<<<(128 * 128 + 255) / 256, b256, 0, stream>>>(W1, Wt1, 128, 128);
  k_wt<<<(128 * 128 + 255) / 256, b256, 0, stream>>>(W2, Wt2, 128, 128);
  k_wt<<<(128 * 128 + 255) / 256, b256, 0, stream>>>(W3, Wt3, 128, 128);
  k_wt<<<(128 * 64 + 255) / 256, b256, 0, stream>>>(W4, Wt4, 128, 64);
  k_wt<<<(64 * 128 + 255) / 256, b256, 0, stream>>>(W5, Wt5, 64, 128);
  k_wt<<<(128 * 128 + 255) / 256, b256, 0, stream>>>(Wd, Wtd, 128, 128);

  const int gemmBlocks = (N + 63) / 64;          // 782
  const int aggBlocks  = (N * 64 + 255) / 256;   // wave per node

  // ---- layer 1: x1 = leaky(gcn(x, W1, b1)) -> bufB ----
  k_hgemm<4><<<gemmBlocks, b256, 0, stream>>>(x, Wt1, nullptr, h16, N, 128, 128,
                                              nullptr, 0, nullptr);
  k_agg128<<<aggBlocks, b256, 0, stream>>>(h16, rowptr, slots, dinv, b1, nullptr,
                                           bufB, N, 1);
  // ---- layer 2: x2 = leaky(gcn(x1, W2, b2)) -> bufC ----
  k_hgemm<4><<<gemmBlocks, b256, 0, stream>>>(bufB, Wt2, nullptr, h16, N, 128, 128,
                                              nullptr, 0, nullptr);
  k_agg128<<<aggBlocks, b256, 0, stream>>>(h16, rowptr, slots, dinv, b2, nullptr,
                                           bufC, N, 1);
  // ---- layer 3: x3 = leaky(gcn(x2, W3, b3)) + x2 -> bufB ----
  k_hgemm<4><<<gemmBlocks, b256, 0, stream>>>(bufC, Wt3, nullptr, h16, N, 128, 128,
                                              nullptr, 0, nullptr);
  k_agg128<<<aggBlocks, b256, 0, stream>>>(h16, rowptr, slots, dinv, b3, bufC,
                                           bufB, N, 1);
  // ---- layer 4: z = gcn(x3, W4, b4) -> zout (fp32) + z16 twin ----
  k_hgemm<2><<<gemmBlocks, b256, 0, stream>>>(bufB, Wt4, nullptr, h16, N, 128, 64,
                                              nullptr, 0, nullptr);
  k_agg64<<<aggBlocks, b256, 0, stream>>>(h16, rowptr, slots, dinv, b4, zout, z16,
                                          N, 0);
  // ---- layer 5 (agg-first, linearity): za = agg64(z16) -> bufB; xr = leaky(za@W5+b5) ----
  k_agg64<<<aggBlocks, b256, 0, stream>>>(z16, rowptr, slots, dinv, nullptr, bufB,
                                          nullptr, N, 0);
  k_hgemm<4><<<gemmBlocks, b256, 0, stream>>>(bufB, Wt5, bufC, nullptr, N, 64, 128,
                                              b5, 1, nullptr);
  // ---- decode: recon = xr @ Wd + bd + x ----
  k_hgemm<4><<<gemmBlocks, b256, 0, stream>>>(bufC, Wtd, recon, nullptr, N, 128, 128,
                                              bd, 0, x);
}